// Round 15
// baseline (194.173 us; speedup 1.0000x reference)
//
#include <hip/hip_runtime.h>
#include <stdint.h>

#define NCLS    80
#define NA_TOT  8400     // 6400 + 1600 + 400
#define NBATCH  32
#define MAXDET  300
#define SSORT   2048
#define RANKCAP 1536
#define CONFTHR 0.001f
#define TILES_PER_IMG 132   // 100 (L0) + 25 (L1) + 7 (L2, clamped)
#define GKCAP   2056        // per-image key slots (2048 + pad)

// ---------------------------------------------------------------------------
// Bit-exact reconstruction of XLA:CPU f32 exp (Eigen/Cephes pexp, no FMA) and
// logistic = 1/(1+exp(-x)). Validated absmax==0.0 rounds 1-14. DO NOT TOUCH.
// ---------------------------------------------------------------------------
__device__ __forceinline__ float xla_expf(float in) {
  const float exp_hi = 88.3762626647950f;
  const float exp_lo = -88.3762626647949f;
  const float LOG2EF = 1.44269504088896341f;
  const float C1 = 0.693359375f;
  const float C2 = -2.12194440e-4f;
  const float p0 = 1.9875691500E-4f, p1 = 1.3981999507E-3f, p2 = 8.3334519073E-3f;
  const float p3 = 4.1665795894E-2f, p4 = 1.6666665459E-1f, p5 = 5.0000001201E-1f;
  float x = fminf(fmaxf(in, exp_lo), exp_hi);
  float fx = floorf(__fadd_rn(__fmul_rn(x, LOG2EF), 0.5f));
  float tmp = __fmul_rn(C1, fx);
  float z   = __fmul_rn(C2, fx);
  x = __fsub_rn(x, tmp);
  x = __fsub_rn(x, z);
  float y = __fadd_rn(__fmul_rn(x, p0), p1);
  y = __fadd_rn(__fmul_rn(y, x), p2);
  y = __fadd_rn(__fmul_rn(y, x), p3);
  y = __fadd_rn(__fmul_rn(y, x), p4);
  y = __fadd_rn(__fmul_rn(y, x), p5);
  y = __fadd_rn(__fmul_rn(y, __fmul_rn(x, x)), x);
  y = __fadd_rn(1.0f, y);
  int m = (int)fx;
  float s = __uint_as_float((uint32_t)(m + 127) << 23);
  float r = __fmul_rn(y, s);
  return fmaxf(r, in);
}

__device__ __forceinline__ float xla_sigmoid(float v) {
  float e = xla_expf(-v);
  float den = __fadd_rn(1.0f, e);
  return 1.0f / den;
}

__device__ __forceinline__ void gload_lds16(const float* gp, float* lp) {
  __builtin_amdgcn_global_load_lds(
      (const __attribute__((address_space(1))) void*)gp,
      (__attribute__((address_space(3))) void*)lp, 16, 0, 0);
}

// ---------------------------------------------------------------------------
// Kernel 1: decode, occupancy-first (r12-measured best: 68.5 us). Verbatim.
// ---------------------------------------------------------------------------
__global__ __launch_bounds__(256) void yolo_decode_kernel(
    const float* __restrict__ f0, const float* __restrict__ f1,
    const float* __restrict__ f2,
    float4* __restrict__ oboxes, float* __restrict__ oconf,
    float* __restrict__ oclsf) {
  __shared__ float sm[144 * 64];                // 36,864 B -> 4 blocks/CU
  int bx  = blockIdx.x;
  int b   = bx / TILES_PER_IMG;
  int r   = bx - b * TILES_PER_IMG;
  int tid = threadIdx.x;
  int lane = tid & 63;
  int wv   = tid >> 6;

  const float* base; int Alvl, W, a0, lvlbase; float stridef;
  if (r < 100)      { base = f0 + (size_t)b * (144 * 6400); W = 80; Alvl = 6400;
                      a0 = r * 64; stridef = 8.0f; lvlbase = 0; }
  else if (r < 125) { base = f1 + (size_t)b * (144 * 1600); W = 40; Alvl = 1600;
                      a0 = (r - 100) * 64; stridef = 16.0f; lvlbase = 6400; }
  else              { base = f2 + (size_t)b * (144 * 400);  W = 20; Alvl = 400;
                      int aa = (r - 125) * 64; a0 = (aa + 64 <= 400) ? aa : 336;
                      stridef = 32.0f; lvlbase = 8000; }   // clamped overlap: benign

  #pragma unroll
  for (int qq = 0; qq < 9; ++qq) {
    int chunk = wv * 9 + qq;
    int c     = chunk * 4 + (lane >> 4);
    int s     = (c >> 4) & 3;
    int idx4  = (lane & 15) ^ (s << 2);
    const float* gp = base + (size_t)c * Alvl + a0 + idx4 * 4;
    gload_lds16(gp, sm + chunk * 256);
  }
  asm volatile("s_waitcnt vmcnt(0)" ::: "memory");
  __builtin_amdgcn_s_barrier();

  const float* S = sm;
  int idx = tid >> 2;
  int w   = tid & 3;
  int ai  = a0 + idx;
  float ax = __fadd_rn((float)(ai % W), 0.5f);
  float ay = __fadd_rn((float)(ai / W), 0.5f);

  int sidx = idx ^ (w << 4);
  float d[16];
  float mx = -INFINITY;
  #pragma unroll
  for (int rr = 0; rr < 16; ++rr) {
    d[rr] = S[(w * 16 + rr) * 64 + sidx];
    mx = fmaxf(mx, d[rr]);
  }
  float e[16]; float ssum = 0.0f;
  #pragma unroll
  for (int rr = 0; rr < 16; ++rr) {
    e[rr] = xla_expf(__fsub_rn(d[rr], mx));
    ssum = __fadd_rn(ssum, e[rr]);
  }
  float acc = 0.0f;
  #pragma unroll
  for (int rr = 0; rr < 16; ++rr) {
    float p = e[rr] / ssum;
    acc = __fadd_rn(acc, __fmul_rn(p, (float)rr));
  }

  int l0 = lane & ~3;
  float lt0 = __shfl(acc, l0 + 0);
  float lt1 = __shfl(acc, l0 + 1);
  float lt2 = __shfl(acc, l0 + 2);
  float lt3 = __shfl(acc, l0 + 3);

  float best = -INFINITY, second = -INFINITY; int bi = 0;
  #pragma unroll 5
  for (int kk = 0; kk < 20; ++kk) {
    int c = 64 + w * 20 + kk;
    float v = S[c * 64 + (idx ^ (((c >> 4) & 3) << 4))];
    if (v > best)        { second = best; best = v; bi = w * 20 + kk; }
    else if (v > second) { second = v; }
  }
  float gb = __shfl(best, l0 + 0), gs = __shfl(second, l0 + 0);
  int   gi = __shfl(bi,   l0 + 0);
  #pragma unroll
  for (int qq = 1; qq < 4; ++qq) {
    float bq = __shfl(best, l0 + qq), sq = __shfl(second, l0 + qq);
    int   iq = __shfl(bi,   l0 + qq);
    if (bq > gb) { gs = fmaxf(gb, sq); gb = bq; gi = iq; }
    else         { gs = fmaxf(gs, bq); }
  }

  float conf = 0.0f; int cls = gi;
  if (__fsub_rn(gb, gs) < 1e-4f || gb > 5.0f) {
    if (w == 0) {
      float bs = -INFINITY; int bj = 0;
      for (int kk = 0; kk < NCLS; ++kk) {
        int c = 64 + kk;
        float v = S[c * 64 + (idx ^ (((c >> 4) & 3) << 4))];
        float s2 = xla_sigmoid(v);
        if (s2 > bs) { bs = s2; bj = kk; }
      }
      conf = bs; cls = bj;
    }
  } else {
    conf = xla_sigmoid(gb);
  }

  if (w == 0) {
    float x1 = __fsub_rn(ax, lt0);
    float y1 = __fsub_rn(ay, lt1);
    float x2 = __fadd_rn(ax, lt2);
    float y2 = __fadd_rn(ay, lt3);
    float cx = __fmul_rn(__fadd_rn(x1, x2), 0.5f);
    float cy = __fmul_rn(__fadd_rn(y1, y2), 0.5f);
    float ww = __fsub_rn(x2, x1);
    float hh = __fsub_rn(y2, y1);
    int t = b * NA_TOT + lvlbase + a0 + idx;
    oboxes[t] = make_float4(__fmul_rn(cx, stridef), __fmul_rn(cy, stridef),
                            __fmul_rn(ww, stridef), __fmul_rn(hh, stridef));
    conf = (conf > CONFTHR) ? conf : 0.0f;
    oconf[t] = conf;
    oclsf[t] = (float)cls;
  }
}

// ---------------------------------------------------------------------------
// Kernel 2: per-image select (r12-validated structure). ONE change: P3 rank
// reads the key stream via wave-uniform GLOBAL loads (TA broadcast through
// L1, VMEM pipe) instead of redundant per-wave ds_read_b128 broadcasts —
// identical compare set, identical ranks.
// ---------------------------------------------------------------------------
struct __align__(16) K2Lds {
  unsigned long long sortkeys[SSORT];   // 16384 B (16B-aligned)
  unsigned confL[NA_TOT];               // 33600 B
  unsigned hist[16][257];               // 16448 B
  unsigned tot[257];
  unsigned Tarr[257];
};                                      // ~68.5 KB

__global__ __launch_bounds__(1024) void yolo_select_kernel(
    const float4* __restrict__ boxes, const float* __restrict__ conf,
    const float* __restrict__ clsf,
    unsigned long long* __restrict__ g_keys,
    float* __restrict__ g_rowd, unsigned long long* __restrict__ g_clsMask) {
  __shared__ K2Lds u;
  __shared__ unsigned s_need, s_prefix, s_found, s_B, s_scnt, s_cut, s_done;
  int b    = blockIdx.x;
  int tid  = threadIdx.x;
  int lane = tid & 63;
  int wv   = tid >> 6;
  const unsigned* confu = (const unsigned*)conf + (size_t)b * NA_TOT;
  float* rowd = g_rowd + (size_t)b * 1024 * 8;
  unsigned long long* cm = g_clsMask + (size_t)b * (NCLS * 16);
  unsigned long long* gk = g_keys + (size_t)b * GKCAP;

  // ---- P0: stage conf bits; zero ws outputs ----
  for (int i = tid; i < NA_TOT; i += 1024) u.confL[i] = confu[i];
  {
    float4 z4 = make_float4(0.f, 0.f, 0.f, 0.f);
    float4* gr = (float4*)rowd;
    for (int k = tid; k < 2048; k += 1024) gr[k] = z4;
  }
  for (int i = tid; i < NCLS * 16; i += 1024) cm[i] = 0ull;
  if (tid == 0) { s_need = 1024; s_prefix = 0; s_cut = 0; s_done = 0; s_scnt = 0; }
  __syncthreads();

  // ---- P1: adaptive 8-bit radix descent (validated r5-r14) ----
  for (int lv = 0; lv < 4; ++lv) {
    __syncthreads();
    if (s_done) break;                          // uniform
    for (int i = tid; i < 16 * 257; i += 1024) ((unsigned*)u.hist)[i] = 0;
    if (tid == 0) { s_found = 0; s_B = 0; }
    __syncthreads();
    unsigned pfx = s_prefix;
    for (int it = 0; it < 9; ++it) {
      int i = tid + it * 1024;
      unsigned c = (i < NA_TOT) ? u.confL[i] : 0u;
      bool in; unsigned bin;
      if (lv == 0)      { in = true;                bin = c >> 23; }
      else if (lv == 1) { in = ((c >> 23) == pfx);  bin = (c >> 15) & 0xFF; }
      else if (lv == 2) { in = ((c >> 15) == pfx);  bin = (c >> 7) & 0xFF; }
      else              { in = ((c >> 7)  == pfx);  bin = c & 0x7F; }
      bool act = (c != 0) && in;
      unsigned long long ab = __ballot(act);
      if (ab) {                                 // wave-uniform branch
        int fl = __ffsll(ab) - 1;
        unsigned fbin = __shfl(bin, fl);
        unsigned long long same = __ballot(act && (bin == fbin));
        if (same == ab) {
          if (lane == fl) atomicAdd(&u.hist[wv][fbin], (unsigned)__popcll(ab));
        } else if (act) {
          atomicAdd(&u.hist[wv][bin], 1u);
        }
      }
    }
    __syncthreads();
    if (tid < 256) {
      unsigned s = 0;
      #pragma unroll
      for (int q = 0; q < 16; ++q) s += u.hist[q][tid];
      u.tot[tid] = s;
    }
    __syncthreads();
    if (tid < 64) {
      unsigned carry = 0;
      if (tid == 0) u.Tarr[256] = 0;
      for (int ch = 3; ch >= 0; --ch) {
        int bb = ch * 64 + tid;
        unsigned v = u.tot[bb];
        #pragma unroll
        for (int off = 1; off < 64; off <<= 1) {
          unsigned t2 = __shfl_down(v, off);
          if (tid + off < 64) v += t2;
        }
        u.Tarr[bb] = v + carry;
        carry += __shfl(v, 0);
      }
    }
    __syncthreads();
    unsigned need = s_need;
    if (tid < 256) {
      unsigned h = u.tot[tid];
      if (h > 0 && u.Tarr[tid + 1] < need && u.Tarr[tid + 1] + h >= need) {
        s_B = (unsigned)tid; s_found = 1;
      }
    }
    __syncthreads();
    if (tid == 0) {
      if (!s_found) { s_cut = 1; s_done = 1; }
      else {
        unsigned B = s_B;
        unsigned selcnt = (1024u - need) + u.Tarr[B];
        if (selcnt <= (unsigned)RANKCAP || lv == 3) {
          s_done = 1;
          if (lv == 0)      s_cut = B << 23;
          else if (lv == 1) s_cut = (s_prefix << 23) | (B << 15);
          else if (lv == 2) s_cut = (s_prefix << 15) | (B << 7);
          else              s_cut = (s_prefix << 7)  | B;
        } else {
          s_need   = need - u.Tarr[B + 1];
          s_prefix = (s_prefix << 8) | B;
        }
      }
    }
  }
  __syncthreads();

  // ---- P2: ballot-aggregated compact (to LDS) ----
  unsigned cut = s_cut;
  for (int it = 0; it < 9; ++it) {
    int i = tid + it * 1024;
    unsigned c = (i < NA_TOT) ? u.confL[i] : 0u;
    bool sel = (c != 0 && c >= cut);
    unsigned long long bal = __ballot(sel);
    unsigned base2 = 0;
    if (lane == 0 && bal) base2 = atomicAdd(&s_scnt, (unsigned)__popcll(bal));
    base2 = __shfl(base2, 0);
    if (sel) {
      unsigned p = base2 + (unsigned)__popcll(bal & ((1ull << lane) - 1ull));
      if (p < SSORT)
        u.sortkeys[p] = ((unsigned long long)c << 32) |
                        (unsigned long long)(0xFFFFFFFFu - (unsigned)i);
    }
  }
  __syncthreads();
  unsigned scnt = s_scnt; if (scnt > SSORT) scnt = SSORT;
  unsigned snp = (scnt + 1u) & ~1u;
  if (tid == 0 && (scnt & 1u)) u.sortkeys[scnt] = 0ull;  // pad
  __syncthreads();

  // ---- P2b: publish keys to global scratch (coalesced, ~12 KB) ----
  for (unsigned p = tid; p < snp; p += 1024) gk[p] = u.sortkeys[p];
  __syncthreads();   // full vmcnt drain (compiler) -> writes visible in L1/L2

  // ---- P3: rank-by-count via wave-uniform GLOBAL reads (L1 broadcast) ----
  for (unsigned e = tid; e < scnt; e += 1024) {
    unsigned long long mykey = u.sortkeys[e];   // per-thread key from LDS
    unsigned r = 0;
    #pragma unroll 4
    for (unsigned j = 0; j < snp; j += 2) {     // uniform addr -> 1 L1 txn
      ulonglong2 kk = *reinterpret_cast<const ulonglong2*>(gk + j);
      r += (kk.x > mykey) ? 1u : 0u;
      r += (kk.y > mykey) ? 1u : 0u;
    }
    if (r < 1024) {                             // == lax.top_k truncation
      unsigned a = 0xFFFFFFFFu - (unsigned)(mykey & 0xFFFFFFFFull);
      float4 cb = boxes[(size_t)b * NA_TOT + a];
      float cls = clsf[(size_t)b * NA_TOT + a];
      float4* gr = (float4*)(rowd + (size_t)r * 8);
      gr[0] = cb;
      gr[1] = make_float4(__uint_as_float((unsigned)(mykey >> 32)), cls, 0.f, 0.f);
      atomicOr(&cm[(int)cls * 16 + (r >> 6)], 1ull << (r & 63));
    }
  }
}

// ---------------------------------------------------------------------------
// Kernel 3: per-image NMS (validated r12, verbatim): parallel row build +
// per-class-parallel walks + parallel popcount emit + sticky tail.
// ---------------------------------------------------------------------------
struct K3Lds {
  unsigned long long rows[1024][16];    // 131072 B, col-swizzled: phys = q^(tid&15)
  float    rowdata[1024][6];            //  24576 B
  unsigned long long am[16];            //    128 B
};                                      // ~155.8 KB

__global__ __launch_bounds__(1024) void yolo_nms_kernel(
    const float* __restrict__ g_rowd,
    const unsigned long long* __restrict__ g_clsMask,
    float* __restrict__ out) {
  __shared__ K3Lds u;
  __shared__ unsigned s_sticky, s_fill;
  int b    = blockIdx.x;
  int tid  = threadIdx.x;
  const unsigned long long* cm = g_clsMask + (size_t)b * (NCLS * 16);

  {
    const float4* gr = (const float4*)(g_rowd + ((size_t)b * 1024 + tid) * 8);
    float4 v0 = gr[0];
    float4 v1 = gr[1];
    u.rowdata[tid][0] = v0.x; u.rowdata[tid][1] = v0.y;
    u.rowdata[tid][2] = v0.z; u.rowdata[tid][3] = v0.w;
    u.rowdata[tid][4] = v1.x; u.rowdata[tid][5] = v1.y;
  }
  {
    unsigned long long* flat = &u.rows[0][0];
    for (int k = tid; k < 1024 * 16; k += 1024) flat[k] = 0ull;
  }
  if (tid < 16) u.am[tid] = 0ull;
  if (tid == 0) { s_sticky = 0xFFFFFFFFu; s_fill = 0; }
  __syncthreads();

  // ---- build suppression-bit rows (same-class pairs; exact IoU sequence) ----
  {
    float cls = u.rowdata[tid][5];
    int c = (int)cls;
    const unsigned long long* cmask = cm + c * 16;
    bool valid = (cmask[tid >> 6] >> (tid & 63)) & 1ull;
    if (valid) {
      float bx0 = u.rowdata[tid][0], by0 = u.rowdata[tid][1];
      float bw0 = u.rowdata[tid][2], bh0 = u.rowdata[tid][3];
      float off = __fmul_rn(cls, 7680.0f);
      float hw  = __fmul_rn(bw0, 0.5f), hh = __fmul_rn(bh0, 0.5f);
      float wx1 = __fadd_rn(__fsub_rn(bx0, hw), off);
      float wy1 = __fadd_rn(__fsub_rn(by0, hh), off);
      float wx2 = __fadd_rn(__fadd_rn(bx0, hw), off);
      float wy2 = __fadd_rn(__fadd_rn(by0, hh), off);
      float a1  = __fmul_rn(__fsub_rn(wx2, wx1), __fsub_rn(wy2, wy1));
      int sw = tid & 15;
      for (int q = 0; q < 16; ++q) {
        unsigned long long m = cmask[q];
        while (m) {
          int bit = __ffsll(m) - 1;
          m &= m - 1ull;
          int j = q * 64 + bit;
          float jx = u.rowdata[j][0], jy = u.rowdata[j][1];
          float jw = u.rowdata[j][2], jh = u.rowdata[j][3];
          float jhw = __fmul_rn(jw, 0.5f), jhh = __fmul_rn(jh, 0.5f);
          float jx1 = __fadd_rn(__fsub_rn(jx, jhw), off);
          float jy1 = __fadd_rn(__fsub_rn(jy, jhh), off);
          float jx2 = __fadd_rn(__fadd_rn(jx, jhw), off);
          float jy2 = __fadd_rn(__fadd_rn(jy, jhh), off);
          float ltx = fmaxf(wx1, jx1), lty = fmaxf(wy1, jy1);
          float rbx = fminf(wx2, jx2), rby = fminf(wy2, jy2);
          float iw = fmaxf(__fsub_rn(rbx, ltx), 0.0f);
          float ih = fmaxf(__fsub_rn(rby, lty), 0.0f);
          float inter = __fmul_rn(iw, ih);
          float a2 = __fmul_rn(__fsub_rn(jx2, jx1), __fsub_rn(jy2, jy1));
          float den = __fadd_rn(__fsub_rn(__fadd_rn(a1, a2), inter), 1e-7f);
          float iou = inter / den;
          if (iou > 0.7f)
            u.rows[tid][(j >> 6) ^ sw] |= (1ull << (j & 63));
        }
      }
    }
  }
  __syncthreads();

  // ---- per-class-parallel walks (80 threads; register alive masks) ----
  if (tid < NCLS) {
    const unsigned long long* cmask = cm + tid * 16;
    unsigned long long alive[16];
    bool any = false;
    #pragma unroll
    for (int q = 0; q < 16; ++q) { alive[q] = cmask[q]; any |= (alive[q] != 0ull); }
    while (any) {
      int r = -1;
      #pragma unroll
      for (int q = 0; q < 16; ++q)
        if (r < 0 && alive[q]) r = q * 64 + (__ffsll(alive[q]) - 1);
      atomicOr(&u.am[r >> 6], 1ull << (r & 63));
      int sw = r & 15;
      unsigned long long selfw = u.rows[r][(r >> 6) ^ sw];
      bool selfbit = (selfw >> (r & 63)) & 1ull;
      if (!selfbit) { atomicMin(&s_sticky, (unsigned)r); break; }  // sticky
      any = false;
      #pragma unroll
      for (int q = 0; q < 16; ++q) {
        alive[q] &= ~u.rows[r][q ^ sw];
        any |= (alive[q] != 0ull);
      }
    }
  }
  __syncthreads();

  // ---- parallel emit: survivor r -> row popc(am below r) ----
  unsigned rs = s_sticky;
  {
    unsigned r = (unsigned)tid;
    bool surv = (u.am[r >> 6] >> (r & 63)) & 1ull;
    if (surv && r <= rs) {
      unsigned e2 = 0;
      int hi = (int)(r >> 6);
      #pragma unroll
      for (int q = 0; q < 16; ++q) {
        unsigned long long m = u.am[q];
        if (q < hi)       e2 += (unsigned)__popcll(m);
        else if (q == hi) e2 += (unsigned)__popcll(m & ((1ull << (r & 63)) - 1ull));
      }
      if (e2 < MAXDET) {
        float* orow = out + (size_t)b * (MAXDET * 6) + (size_t)e2 * 6;
        orow[0] = u.rowdata[r][0];
        orow[1] = u.rowdata[r][1];
        orow[2] = u.rowdata[r][2];
        orow[3] = u.rowdata[r][3];
        orow[4] = u.rowdata[r][4];
        orow[5] = u.rowdata[r][5];
      }
    }
  }
  if (tid == 0) {
    unsigned fill;
    if (rs != 0xFFFFFFFFu) {
      unsigned es = 0;
      int hi = (int)(rs >> 6);
      #pragma unroll
      for (int q = 0; q < 16; ++q) {
        unsigned long long m = u.am[q];
        if (q < hi)       es += (unsigned)__popcll(m);
        else if (q == hi) es += (unsigned)__popcll(m & ((1ull << (rs & 63)) - 1ull));
      }
      fill = es + 1;
    } else {
      unsigned S = 0;
      #pragma unroll
      for (int q = 0; q < 16; ++q) S += (unsigned)__popcll(u.am[q]);
      fill = S;
    }
    s_fill = (fill > (unsigned)MAXDET) ? (unsigned)MAXDET : fill;
  }
  __syncthreads();

  {
    unsigned fill = s_fill;
    bool st = (rs != 0xFFFFFFFFu);
    float* orow = out + (size_t)b * (MAXDET * 6);
    for (int i = (int)fill * 6 + tid; i < MAXDET * 6; i += 1024) {
      float v = 0.0f;
      if (st) v = u.rowdata[rs][i - (i / 6) * 6];
      orow[i] = v;
    }
  }
}

extern "C" void kernel_launch(void* const* d_in, const int* in_sizes, int n_in,
                              void* d_out, int out_size, void* d_ws, size_t ws_size,
                              hipStream_t stream) {
  const float* f0 = (const float*)d_in[0];
  const float* f1 = (const float*)d_in[1];
  const float* f2 = (const float*)d_in[2];
  float* out = (float*)d_out;

  char* ws = (char*)d_ws;
  float4* boxes = (float4*)ws;                                       // 4,300,800
  float*  conf  = (float*)(ws + (size_t)NBATCH * NA_TOT * 16);       // 1,075,200
  float*  clsf  = (float*)(ws + (size_t)NBATCH * NA_TOT * 20);       // 1,075,200
  size_t off = (size_t)NBATCH * NA_TOT * 24;                         // 6,451,200
  float*  rowd  = (float*)(ws + off);                       off += 1048576;
  unsigned long long* clsm = (unsigned long long*)(ws + off); off += 327680;
  unsigned long long* gkeys = (unsigned long long*)(ws + off);

  yolo_decode_kernel<<<NBATCH * TILES_PER_IMG, 256, 0, stream>>>(
      f0, f1, f2, boxes, conf, clsf);
  yolo_select_kernel<<<NBATCH, 1024, 0, stream>>>(boxes, conf, clsf,
                                                  gkeys, rowd, clsm);
  yolo_nms_kernel<<<NBATCH, 1024, 0, stream>>>(rowd, clsm, out);
}

// Round 16
// 154.891 us; speedup vs baseline: 1.2536x; 1.2536x over previous
//
#include <hip/hip_runtime.h>
#include <stdint.h>

#define NCLS    80
#define NA_TOT  8400     // 6400 + 1600 + 400
#define NBATCH  32
#define MAXDET  300
#define SSORT   2048
#define RANKCAP 1536
#define CONFTHR 0.001f
#define TILES_PER_IMG 132   // 100 (L0) + 25 (L1) + 7 (L2, clamped)

// ---------------------------------------------------------------------------
// Bit-exact reconstruction of XLA:CPU f32 exp (Eigen/Cephes pexp, no FMA) and
// logistic = 1/(1+exp(-x)). Validated absmax==0.0 rounds 1-15. DO NOT TOUCH.
// ---------------------------------------------------------------------------
__device__ __forceinline__ float xla_expf(float in) {
  const float exp_hi = 88.3762626647950f;
  const float exp_lo = -88.3762626647949f;
  const float LOG2EF = 1.44269504088896341f;
  const float C1 = 0.693359375f;
  const float C2 = -2.12194440e-4f;
  const float p0 = 1.9875691500E-4f, p1 = 1.3981999507E-3f, p2 = 8.3334519073E-3f;
  const float p3 = 4.1665795894E-2f, p4 = 1.6666665459E-1f, p5 = 5.0000001201E-1f;
  float x = fminf(fmaxf(in, exp_lo), exp_hi);
  float fx = floorf(__fadd_rn(__fmul_rn(x, LOG2EF), 0.5f));
  float tmp = __fmul_rn(C1, fx);
  float z   = __fmul_rn(C2, fx);
  x = __fsub_rn(x, tmp);
  x = __fsub_rn(x, z);
  float y = __fadd_rn(__fmul_rn(x, p0), p1);
  y = __fadd_rn(__fmul_rn(y, x), p2);
  y = __fadd_rn(__fmul_rn(y, x), p3);
  y = __fadd_rn(__fmul_rn(y, x), p4);
  y = __fadd_rn(__fmul_rn(y, x), p5);
  y = __fadd_rn(__fmul_rn(y, __fmul_rn(x, x)), x);
  y = __fadd_rn(1.0f, y);
  int m = (int)fx;
  float s = __uint_as_float((uint32_t)(m + 127) << 23);
  float r = __fmul_rn(y, s);
  return fmaxf(r, in);
}

__device__ __forceinline__ float xla_sigmoid(float v) {
  float e = xla_expf(-v);
  float den = __fadd_rn(1.0f, e);
  return 1.0f / den;
}

__device__ __forceinline__ void gload_lds16(const float* gp, float* lp) {
  __builtin_amdgcn_global_load_lds(
      (const __attribute__((address_space(1))) void*)gp,
      (__attribute__((address_space(3))) void*)lp, 16, 0, 0);
}

// ---------------------------------------------------------------------------
// Kernel 1: conf/cls ONLY (boxes deferred to K2b). r12's validated staging +
// class-scan structure, restricted to the 80 class channels (20 KB LDS).
// ---------------------------------------------------------------------------
__global__ __launch_bounds__(256) void yolo_confcls_kernel(
    const float* __restrict__ f0, const float* __restrict__ f1,
    const float* __restrict__ f2,
    float* __restrict__ oconf, float* __restrict__ oclsf) {
  __shared__ float sm[80 * 64];                 // 20,480 B -> 8 blocks/CU
  int bx  = blockIdx.x;
  int b   = bx / TILES_PER_IMG;
  int r   = bx - b * TILES_PER_IMG;
  int tid = threadIdx.x;
  int lane = tid & 63;
  int wv   = tid >> 6;

  const float* base; int Alvl, a0, lvlbase;
  if (r < 100)      { base = f0 + (size_t)b * (144 * 6400); Alvl = 6400;
                      a0 = r * 64; lvlbase = 0; }
  else if (r < 125) { base = f1 + (size_t)b * (144 * 1600); Alvl = 1600;
                      a0 = (r - 100) * 64; lvlbase = 6400; }
  else              { base = f2 + (size_t)b * (144 * 400);  Alvl = 400;
                      int aa = (r - 125) * 64; a0 = (aa + 64 <= 400) ? aa : 336;
                      lvlbase = 8000; }        // clamped overlap: benign

  // ---- STAGE class channels: 20 chunks (4 ch each); wave wv stages 5 ----
  #pragma unroll
  for (int qq = 0; qq < 5; ++qq) {
    int chunk = wv * 5 + qq;                    // 0..19
    int c     = chunk * 4 + (lane >> 4);        // class-channel idx 0..79
    int s     = (c >> 4) & 3;
    int idx4  = (lane & 15) ^ (s << 2);         // source-side swizzle (16B)
    gload_lds16(base + (size_t)(64 + c) * Alvl + a0 + idx4 * 4, sm + chunk * 256);
  }
  asm volatile("s_waitcnt vmcnt(0)" ::: "memory");
  __builtin_amdgcn_s_barrier();

  const float* S = sm;
  int idx = tid >> 2;                           // anchor in tile
  int w   = tid & 3;                            // worker

  // ---- class top-2 scan (validated semantics; reader keyed on c=0..79) ----
  float best = -INFINITY, second = -INFINITY; int bi = 0;
  #pragma unroll 5
  for (int kk = 0; kk < 20; ++kk) {
    int c = w * 20 + kk;
    float v = S[c * 64 + (idx ^ (((c >> 4) & 3) << 4))];
    if (v > best)        { second = best; best = v; bi = c; }
    else if (v > second) { second = v; }
  }
  int l0 = lane & ~3;
  float gb = __shfl(best, l0 + 0), gs = __shfl(second, l0 + 0);
  int   gi = __shfl(bi,   l0 + 0);
  #pragma unroll
  for (int qq = 1; qq < 4; ++qq) {
    float bq = __shfl(best, l0 + qq), sq = __shfl(second, l0 + qq);
    int   iq = __shfl(bi,   l0 + qq);
    if (bq > gb) { gs = fmaxf(gb, sq); gb = bq; gi = iq; }
    else         { gs = fmaxf(gs, bq); }
  }

  float conf = 0.0f; int cls = gi;
  if (__fsub_rn(gb, gs) < 1e-4f || gb > 5.0f) {
    // exact slow path (rare): identical to validated r1 80-sigmoid scan
    if (w == 0) {
      float bs = -INFINITY; int bj = 0;
      for (int kk = 0; kk < NCLS; ++kk) {
        float v = S[kk * 64 + (idx ^ (((kk >> 4) & 3) << 4))];
        float s2 = xla_sigmoid(v);
        if (s2 > bs) { bs = s2; bj = kk; }
      }
      conf = bs; cls = bj;
    }
  } else {
    conf = xla_sigmoid(gb);
  }

  if (w == 0) {
    int t = b * NA_TOT + lvlbase + a0 + idx;
    conf = (conf > CONFTHR) ? conf : 0.0f;
    oconf[t] = conf;
    oclsf[t] = (float)cls;
  }
}

// ---------------------------------------------------------------------------
// Kernel 2: per-image select (r12-validated verbatim; scatter stores
// (conf, cls, anchor-bits) — box deferred to K2b).
// ---------------------------------------------------------------------------
struct __align__(16) K2Lds {
  unsigned long long sortkeys[SSORT];   // 16384 B (16B-aligned)
  unsigned confL[NA_TOT];               // 33600 B
  unsigned hist[16][257];               // 16448 B
  unsigned tot[257];
  unsigned Tarr[257];
};                                      // ~68.5 KB

__global__ __launch_bounds__(1024) void yolo_select_kernel(
    const float* __restrict__ conf, const float* __restrict__ clsf,
    float* __restrict__ g_rowd, unsigned long long* __restrict__ g_clsMask) {
  __shared__ K2Lds u;
  __shared__ unsigned s_need, s_prefix, s_found, s_B, s_scnt, s_cut, s_done;
  int b    = blockIdx.x;
  int tid  = threadIdx.x;
  int lane = tid & 63;
  int wv   = tid >> 6;
  const unsigned* confu = (const unsigned*)conf + (size_t)b * NA_TOT;
  float* rowd = g_rowd + (size_t)b * 1024 * 8;
  unsigned long long* cm = g_clsMask + (size_t)b * (NCLS * 16);

  // ---- P0: stage conf bits; zero ws outputs ----
  for (int i = tid; i < NA_TOT; i += 1024) u.confL[i] = confu[i];
  {
    float4 z4 = make_float4(0.f, 0.f, 0.f, 0.f);
    float4* gr = (float4*)rowd;
    for (int k = tid; k < 2048; k += 1024) gr[k] = z4;
  }
  for (int i = tid; i < NCLS * 16; i += 1024) cm[i] = 0ull;
  if (tid == 0) { s_need = 1024; s_prefix = 0; s_cut = 0; s_done = 0; s_scnt = 0; }
  __syncthreads();

  // ---- P1: adaptive 8-bit radix descent (validated r5-r15) ----
  for (int lv = 0; lv < 4; ++lv) {
    __syncthreads();
    if (s_done) break;                          // uniform
    for (int i = tid; i < 16 * 257; i += 1024) ((unsigned*)u.hist)[i] = 0;
    if (tid == 0) { s_found = 0; s_B = 0; }
    __syncthreads();
    unsigned pfx = s_prefix;
    for (int it = 0; it < 9; ++it) {
      int i = tid + it * 1024;
      unsigned c = (i < NA_TOT) ? u.confL[i] : 0u;
      bool in; unsigned bin;
      if (lv == 0)      { in = true;                bin = c >> 23; }
      else if (lv == 1) { in = ((c >> 23) == pfx);  bin = (c >> 15) & 0xFF; }
      else if (lv == 2) { in = ((c >> 15) == pfx);  bin = (c >> 7) & 0xFF; }
      else              { in = ((c >> 7)  == pfx);  bin = c & 0x7F; }
      bool act = (c != 0) && in;
      unsigned long long ab = __ballot(act);
      if (ab) {                                 // wave-uniform branch
        int fl = __ffsll(ab) - 1;
        unsigned fbin = __shfl(bin, fl);
        unsigned long long same = __ballot(act && (bin == fbin));
        if (same == ab) {
          if (lane == fl) atomicAdd(&u.hist[wv][fbin], (unsigned)__popcll(ab));
        } else if (act) {
          atomicAdd(&u.hist[wv][bin], 1u);
        }
      }
    }
    __syncthreads();
    if (tid < 256) {
      unsigned s = 0;
      #pragma unroll
      for (int q = 0; q < 16; ++q) s += u.hist[q][tid];
      u.tot[tid] = s;
    }
    __syncthreads();
    if (tid < 64) {
      unsigned carry = 0;
      if (tid == 0) u.Tarr[256] = 0;
      for (int ch = 3; ch >= 0; --ch) {
        int bb = ch * 64 + tid;
        unsigned v = u.tot[bb];
        #pragma unroll
        for (int off = 1; off < 64; off <<= 1) {
          unsigned t2 = __shfl_down(v, off);
          if (tid + off < 64) v += t2;
        }
        u.Tarr[bb] = v + carry;
        carry += __shfl(v, 0);
      }
    }
    __syncthreads();
    unsigned need = s_need;
    if (tid < 256) {
      unsigned h = u.tot[tid];
      if (h > 0 && u.Tarr[tid + 1] < need && u.Tarr[tid + 1] + h >= need) {
        s_B = (unsigned)tid; s_found = 1;
      }
    }
    __syncthreads();
    if (tid == 0) {
      if (!s_found) { s_cut = 1; s_done = 1; }
      else {
        unsigned B = s_B;
        unsigned selcnt = (1024u - need) + u.Tarr[B];
        if (selcnt <= (unsigned)RANKCAP || lv == 3) {
          s_done = 1;
          if (lv == 0)      s_cut = B << 23;
          else if (lv == 1) s_cut = (s_prefix << 23) | (B << 15);
          else if (lv == 2) s_cut = (s_prefix << 15) | (B << 7);
          else              s_cut = (s_prefix << 7)  | B;
        } else {
          s_need   = need - u.Tarr[B + 1];
          s_prefix = (s_prefix << 8) | B;
        }
      }
    }
  }
  __syncthreads();

  // ---- P2: ballot-aggregated compact ----
  unsigned cut = s_cut;
  for (int it = 0; it < 9; ++it) {
    int i = tid + it * 1024;
    unsigned c = (i < NA_TOT) ? u.confL[i] : 0u;
    bool sel = (c != 0 && c >= cut);
    unsigned long long bal = __ballot(sel);
    unsigned base2 = 0;
    if (lane == 0 && bal) base2 = atomicAdd(&s_scnt, (unsigned)__popcll(bal));
    base2 = __shfl(base2, 0);
    if (sel) {
      unsigned p = base2 + (unsigned)__popcll(bal & ((1ull << lane) - 1ull));
      if (p < SSORT)
        u.sortkeys[p] = ((unsigned long long)c << 32) |
                        (unsigned long long)(0xFFFFFFFFu - (unsigned)i);
    }
  }
  __syncthreads();
  unsigned scnt = s_scnt; if (scnt > SSORT) scnt = SSORT;
  unsigned snp = (scnt + 1u) & ~1u;
  if (tid == 0 && (scnt & 1u)) u.sortkeys[scnt] = 0ull;  // pad for b128
  __syncthreads();

  // ---- P3: rank-by-count (b128 LDS broadcast; r12-validated) + scatter ----
  for (unsigned e = tid; e < scnt; e += 1024) {
    unsigned long long mykey = u.sortkeys[e];
    unsigned r = 0;
    #pragma unroll 4
    for (unsigned j = 0; j < snp; j += 2) {
      ulonglong2 kk = *reinterpret_cast<const ulonglong2*>(&u.sortkeys[j]);
      r += (kk.x > mykey) ? 1u : 0u;
      r += (kk.y > mykey) ? 1u : 0u;
    }
    if (r < 1024) {                             // == lax.top_k truncation
      unsigned a = 0xFFFFFFFFu - (unsigned)(mykey & 0xFFFFFFFFull);
      float cls = clsf[(size_t)b * NA_TOT + a];
      float4* gr = (float4*)(rowd + (size_t)r * 8);
      gr[1] = make_float4(__uint_as_float((unsigned)(mykey >> 32)), cls,
                          __uint_as_float(a), 0.f);
      atomicOr(&cm[(int)cls * 16 + (r >> 6)], 1ull << (r & 63));
    }
  }
}

// ---------------------------------------------------------------------------
// Kernel 2b: DFL box decode for SELECTED anchors only (r1-verbatim per-anchor
// arithmetic). 8 blocks/image x 128 threads; thread = rank.
// ---------------------------------------------------------------------------
__global__ __launch_bounds__(128) void yolo_dfl_kernel(
    const float* __restrict__ f0, const float* __restrict__ f1,
    const float* __restrict__ f2, float* __restrict__ g_rowd) {
  int bx   = blockIdx.x;
  int b    = bx >> 3;
  int part = bx & 7;
  int r    = part * 128 + threadIdx.x;          // rank 0..1023
  float* rd = g_rowd + ((size_t)b * 1024 + r) * 8;
  float conf = rd[4];
  if (conf == 0.0f) return;                     // invalid rank: box stays 0
  unsigned a = __float_as_uint(rd[6]);

  const float* base; int ai, W; float stridef;
  if (a < 6400)      { base = f0 + (size_t)b * (144 * 6400); ai = a;        W = 80; stridef = 8.0f;  }
  else if (a < 8000) { base = f1 + (size_t)b * (144 * 1600); ai = a - 6400; W = 40; stridef = 16.0f; }
  else               { base = f2 + (size_t)b * (144 * 400);  ai = a - 8000; W = 20; stridef = 32.0f; }
  int Alvl = W * W;
  const float* cptr = base + ai;
  float ax = __fadd_rn((float)(ai % W), 0.5f);
  float ay = __fadd_rn((float)(ai / W), 0.5f);

  // ---- DFL softmax-expectation (bit-exact r1 sequence, verbatim) ----
  float ltrb[4];
  #pragma unroll
  for (int fs = 0; fs < 4; ++fs) {
    float d[16];
    float mx = -INFINITY;
    #pragma unroll
    for (int rr = 0; rr < 16; ++rr) {
      d[rr] = cptr[(size_t)(fs * 16 + rr) * Alvl];
      mx = fmaxf(mx, d[rr]);
    }
    float e[16]; float ssum = 0.0f;
    #pragma unroll
    for (int rr = 0; rr < 16; ++rr) {
      e[rr] = xla_expf(__fsub_rn(d[rr], mx));
      ssum = __fadd_rn(ssum, e[rr]);
    }
    float acc = 0.0f;
    #pragma unroll
    for (int rr = 0; rr < 16; ++rr) {
      float p = e[rr] / ssum;
      acc = __fadd_rn(acc, __fmul_rn(p, (float)rr));
    }
    ltrb[fs] = acc;
  }

  float x1 = __fsub_rn(ax, ltrb[0]);
  float y1 = __fsub_rn(ay, ltrb[1]);
  float x2 = __fadd_rn(ax, ltrb[2]);
  float y2 = __fadd_rn(ay, ltrb[3]);
  float cx = __fmul_rn(__fadd_rn(x1, x2), 0.5f);
  float cy = __fmul_rn(__fadd_rn(y1, y2), 0.5f);
  float w  = __fsub_rn(x2, x1);
  float h  = __fsub_rn(y2, y1);
  *reinterpret_cast<float4*>(rd) =
      make_float4(__fmul_rn(cx, stridef), __fmul_rn(cy, stridef),
                  __fmul_rn(w, stridef),  __fmul_rn(h, stridef));
}

// ---------------------------------------------------------------------------
// Kernel 3: per-image NMS (r12-validated verbatim): parallel row build +
// per-class-parallel walks + parallel popcount emit + sticky tail.
// ---------------------------------------------------------------------------
struct K3Lds {
  unsigned long long rows[1024][16];    // 131072 B, col-swizzled: phys = q^(tid&15)
  float    rowdata[1024][6];            //  24576 B
  unsigned long long am[16];            //    128 B
};                                      // ~155.8 KB

__global__ __launch_bounds__(1024) void yolo_nms_kernel(
    const float* __restrict__ g_rowd,
    const unsigned long long* __restrict__ g_clsMask,
    float* __restrict__ out) {
  __shared__ K3Lds u;
  __shared__ unsigned s_sticky, s_fill;
  int b    = blockIdx.x;
  int tid  = threadIdx.x;
  const unsigned long long* cm = g_clsMask + (size_t)b * (NCLS * 16);

  {
    const float4* gr = (const float4*)(g_rowd + ((size_t)b * 1024 + tid) * 8);
    float4 v0 = gr[0];
    float4 v1 = gr[1];
    u.rowdata[tid][0] = v0.x; u.rowdata[tid][1] = v0.y;
    u.rowdata[tid][2] = v0.z; u.rowdata[tid][3] = v0.w;
    u.rowdata[tid][4] = v1.x; u.rowdata[tid][5] = v1.y;
  }
  {
    unsigned long long* flat = &u.rows[0][0];
    for (int k = tid; k < 1024 * 16; k += 1024) flat[k] = 0ull;
  }
  if (tid < 16) u.am[tid] = 0ull;
  if (tid == 0) { s_sticky = 0xFFFFFFFFu; s_fill = 0; }
  __syncthreads();

  // ---- build suppression-bit rows (same-class pairs; exact IoU sequence) ----
  {
    float cls = u.rowdata[tid][5];
    int c = (int)cls;
    const unsigned long long* cmask = cm + c * 16;
    bool valid = (cmask[tid >> 6] >> (tid & 63)) & 1ull;
    if (valid) {
      float bx0 = u.rowdata[tid][0], by0 = u.rowdata[tid][1];
      float bw0 = u.rowdata[tid][2], bh0 = u.rowdata[tid][3];
      float off = __fmul_rn(cls, 7680.0f);
      float hw  = __fmul_rn(bw0, 0.5f), hh = __fmul_rn(bh0, 0.5f);
      float wx1 = __fadd_rn(__fsub_rn(bx0, hw), off);
      float wy1 = __fadd_rn(__fsub_rn(by0, hh), off);
      float wx2 = __fadd_rn(__fadd_rn(bx0, hw), off);
      float wy2 = __fadd_rn(__fadd_rn(by0, hh), off);
      float a1  = __fmul_rn(__fsub_rn(wx2, wx1), __fsub_rn(wy2, wy1));
      int sw = tid & 15;
      for (int q = 0; q < 16; ++q) {
        unsigned long long m = cmask[q];
        while (m) {
          int bit = __ffsll(m) - 1;
          m &= m - 1ull;
          int j = q * 64 + bit;
          float jx = u.rowdata[j][0], jy = u.rowdata[j][1];
          float jw = u.rowdata[j][2], jh = u.rowdata[j][3];
          float jhw = __fmul_rn(jw, 0.5f), jhh = __fmul_rn(jh, 0.5f);
          float jx1 = __fadd_rn(__fsub_rn(jx, jhw), off);
          float jy1 = __fadd_rn(__fsub_rn(jy, jhh), off);
          float jx2 = __fadd_rn(__fadd_rn(jx, jhw), off);
          float jy2 = __fadd_rn(__fadd_rn(jy, jhh), off);
          float ltx = fmaxf(wx1, jx1), lty = fmaxf(wy1, jy1);
          float rbx = fminf(wx2, jx2), rby = fminf(wy2, jy2);
          float iw = fmaxf(__fsub_rn(rbx, ltx), 0.0f);
          float ih = fmaxf(__fsub_rn(rby, lty), 0.0f);
          float inter = __fmul_rn(iw, ih);
          float a2 = __fmul_rn(__fsub_rn(jx2, jx1), __fsub_rn(jy2, jy1));
          float den = __fadd_rn(__fsub_rn(__fadd_rn(a1, a2), inter), 1e-7f);
          float iou = inter / den;
          if (iou > 0.7f)
            u.rows[tid][(j >> 6) ^ sw] |= (1ull << (j & 63));
        }
      }
    }
  }
  __syncthreads();

  // ---- per-class-parallel walks (80 threads; register alive masks) ----
  if (tid < NCLS) {
    const unsigned long long* cmask = cm + tid * 16;
    unsigned long long alive[16];
    bool any = false;
    #pragma unroll
    for (int q = 0; q < 16; ++q) { alive[q] = cmask[q]; any |= (alive[q] != 0ull); }
    while (any) {
      int r = -1;
      #pragma unroll
      for (int q = 0; q < 16; ++q)
        if (r < 0 && alive[q]) r = q * 64 + (__ffsll(alive[q]) - 1);
      atomicOr(&u.am[r >> 6], 1ull << (r & 63));
      int sw = r & 15;
      unsigned long long selfw = u.rows[r][(r >> 6) ^ sw];
      bool selfbit = (selfw >> (r & 63)) & 1ull;
      if (!selfbit) { atomicMin(&s_sticky, (unsigned)r); break; }  // sticky
      any = false;
      #pragma unroll
      for (int q = 0; q < 16; ++q) {
        alive[q] &= ~u.rows[r][q ^ sw];
        any |= (alive[q] != 0ull);
      }
    }
  }
  __syncthreads();

  // ---- parallel emit: survivor r -> row popc(am below r) ----
  unsigned rs = s_sticky;
  {
    unsigned r = (unsigned)tid;
    bool surv = (u.am[r >> 6] >> (r & 63)) & 1ull;
    if (surv && r <= rs) {
      unsigned e2 = 0;
      int hi = (int)(r >> 6);
      #pragma unroll
      for (int q = 0; q < 16; ++q) {
        unsigned long long m = u.am[q];
        if (q < hi)       e2 += (unsigned)__popcll(m);
        else if (q == hi) e2 += (unsigned)__popcll(m & ((1ull << (r & 63)) - 1ull));
      }
      if (e2 < MAXDET) {
        float* orow = out + (size_t)b * (MAXDET * 6) + (size_t)e2 * 6;
        orow[0] = u.rowdata[r][0];
        orow[1] = u.rowdata[r][1];
        orow[2] = u.rowdata[r][2];
        orow[3] = u.rowdata[r][3];
        orow[4] = u.rowdata[r][4];
        orow[5] = u.rowdata[r][5];
      }
    }
  }
  if (tid == 0) {
    unsigned fill;
    if (rs != 0xFFFFFFFFu) {
      unsigned es = 0;
      int hi = (int)(rs >> 6);
      #pragma unroll
      for (int q = 0; q < 16; ++q) {
        unsigned long long m = u.am[q];
        if (q < hi)       es += (unsigned)__popcll(m);
        else if (q == hi) es += (unsigned)__popcll(m & ((1ull << (rs & 63)) - 1ull));
      }
      fill = es + 1;
    } else {
      unsigned S = 0;
      #pragma unroll
      for (int q = 0; q < 16; ++q) S += (unsigned)__popcll(u.am[q]);
      fill = S;
    }
    s_fill = (fill > (unsigned)MAXDET) ? (unsigned)MAXDET : fill;
  }
  __syncthreads();

  {
    unsigned fill = s_fill;
    bool st = (rs != 0xFFFFFFFFu);
    float* orow = out + (size_t)b * (MAXDET * 6);
    for (int i = (int)fill * 6 + tid; i < MAXDET * 6; i += 1024) {
      float v = 0.0f;
      if (st) v = u.rowdata[rs][i - (i / 6) * 6];
      orow[i] = v;
    }
  }
}

extern "C" void kernel_launch(void* const* d_in, const int* in_sizes, int n_in,
                              void* d_out, int out_size, void* d_ws, size_t ws_size,
                              hipStream_t stream) {
  const float* f0 = (const float*)d_in[0];
  const float* f1 = (const float*)d_in[1];
  const float* f2 = (const float*)d_in[2];
  float* out = (float*)d_out;

  char* ws = (char*)d_ws;
  float* conf = (float*)ws;                                    // 1,075,200 B
  float* clsf = (float*)(ws + (size_t)NBATCH * NA_TOT * 4);    // 1,075,200 B
  size_t off  = (size_t)NBATCH * NA_TOT * 8;
  float* rowd = (float*)(ws + off);             off += 1048576;
  unsigned long long* clsm = (unsigned long long*)(ws + off);  // 327,680 B

  yolo_confcls_kernel<<<NBATCH * TILES_PER_IMG, 256, 0, stream>>>(
      f0, f1, f2, conf, clsf);
  yolo_select_kernel<<<NBATCH, 1024, 0, stream>>>(conf, clsf, rowd, clsm);
  yolo_dfl_kernel<<<NBATCH * 8, 128, 0, stream>>>(f0, f1, f2, rowd);
  yolo_nms_kernel<<<NBATCH, 1024, 0, stream>>>(rowd, clsm, out);
}

// Round 17
// 135.741 us; speedup vs baseline: 1.4305x; 1.1411x over previous
//
#include <hip/hip_runtime.h>
#include <stdint.h>

#define NCLS    80
#define NA_TOT  8400     // 6400 + 1600 + 400
#define NBATCH  32
#define MAXDET  300
#define SSORT   2048
#define RANKCAP 1536
#define CONFTHR 0.001f
#define TILES_PER_IMG 132   // 100 (L0) + 25 (L1) + 7 (L2, clamped)

// ---------------------------------------------------------------------------
// Bit-exact reconstruction of XLA:CPU f32 exp (Eigen/Cephes pexp, no FMA) and
// logistic = 1/(1+exp(-x)). Validated absmax==0.0 rounds 1-16. DO NOT TOUCH.
// ---------------------------------------------------------------------------
__device__ __forceinline__ float xla_expf(float in) {
  const float exp_hi = 88.3762626647950f;
  const float exp_lo = -88.3762626647949f;
  const float LOG2EF = 1.44269504088896341f;
  const float C1 = 0.693359375f;
  const float C2 = -2.12194440e-4f;
  const float p0 = 1.9875691500E-4f, p1 = 1.3981999507E-3f, p2 = 8.3334519073E-3f;
  const float p3 = 4.1665795894E-2f, p4 = 1.6666665459E-1f, p5 = 5.0000001201E-1f;
  float x = fminf(fmaxf(in, exp_lo), exp_hi);
  float fx = floorf(__fadd_rn(__fmul_rn(x, LOG2EF), 0.5f));
  float tmp = __fmul_rn(C1, fx);
  float z   = __fmul_rn(C2, fx);
  x = __fsub_rn(x, tmp);
  x = __fsub_rn(x, z);
  float y = __fadd_rn(__fmul_rn(x, p0), p1);
  y = __fadd_rn(__fmul_rn(y, x), p2);
  y = __fadd_rn(__fmul_rn(y, x), p3);
  y = __fadd_rn(__fmul_rn(y, x), p4);
  y = __fadd_rn(__fmul_rn(y, x), p5);
  y = __fadd_rn(__fmul_rn(y, __fmul_rn(x, x)), x);
  y = __fadd_rn(1.0f, y);
  int m = (int)fx;
  float s = __uint_as_float((uint32_t)(m + 127) << 23);
  float r = __fmul_rn(y, s);
  return fmaxf(r, in);
}

__device__ __forceinline__ float xla_sigmoid(float v) {
  float e = xla_expf(-v);
  float den = __fadd_rn(1.0f, e);
  return 1.0f / den;
}

__device__ __forceinline__ void gload_lds16(const float* gp, float* lp) {
  __builtin_amdgcn_global_load_lds(
      (const __attribute__((address_space(1))) void*)gp,
      (__attribute__((address_space(3))) void*)lp, 16, 0, 0);
}

// ---------------------------------------------------------------------------
// Kernel 1: decode v4 — per-wave autonomy, BARRIER-FREE. Each wave stages its
// own 16 anchors x 144 channels (9 KB, row-major [144][16], 64B rows) via 9
// gload_lds chunks, waits only its own vmcnt(0), computes. No s_barrier.
// Per-anchor FP sequences verbatim r1/r12; only lane->anchor mapping differs
// (anchor = lane&15, worker = lane>>4; worker-0-first merge order kept).
// ---------------------------------------------------------------------------
__global__ __launch_bounds__(256) void yolo_decode_kernel(
    const float* __restrict__ f0, const float* __restrict__ f1,
    const float* __restrict__ f2,
    float4* __restrict__ oboxes, float* __restrict__ oconf,
    float* __restrict__ oclsf) {
  __shared__ float sm[4 * 144 * 16];            // 36,864 B -> 4 blocks/CU
  int bx  = blockIdx.x;
  int b   = bx / TILES_PER_IMG;
  int r   = bx - b * TILES_PER_IMG;
  int tid = threadIdx.x;
  int lane = tid & 63;
  int wv   = tid >> 6;

  const float* base; int Alvl, W, a0, lvlbase; float stridef;
  if (r < 100)      { base = f0 + (size_t)b * (144 * 6400); W = 80; Alvl = 6400;
                      a0 = r * 64; stridef = 8.0f; lvlbase = 0; }
  else if (r < 125) { base = f1 + (size_t)b * (144 * 1600); W = 40; Alvl = 1600;
                      a0 = (r - 100) * 64; stridef = 16.0f; lvlbase = 6400; }
  else              { base = f2 + (size_t)b * (144 * 400);  W = 20; Alvl = 400;
                      int aa = (r - 125) * 64; a0 = (aa + 64 <= 400) ? aa : 336;
                      stridef = 32.0f; lvlbase = 8000; }   // clamped overlap: benign

  int a0w = a0 + wv * 16;                       // this wave's 16 anchors
  float* Sw = sm + wv * (144 * 16);             // this wave's 9 KB region

  // ---- STAGE (per-wave): 9 chunks x [16 ch x 16 anchors]; linear dest ----
  #pragma unroll
  for (int k = 0; k < 9; ++k) {
    int ch = k * 16 + (lane >> 2);              // channel 0..143
    const float* gp = base + (size_t)ch * Alvl + a0w + (lane & 3) * 4;
    gload_lds16(gp, Sw + k * 256);              // HW: +lane*16B -> S[ch][.]
  }
  asm volatile("s_waitcnt vmcnt(0)" ::: "memory");   // own loads only
  __builtin_amdgcn_sched_barrier(0);

  int idx = lane & 15;                          // anchor within wave
  int w   = lane >> 4;                          // worker (DFL side / cls slice)
  int ai  = a0w + idx;
  float ax = __fadd_rn((float)(ai % W), 0.5f);
  float ay = __fadd_rn((float)(ai / W), 0.5f);

  // ---- DFL side w (verbatim r1 sequence; source S[w*16+rr][idx]) ----
  float d[16];
  float mx = -INFINITY;
  #pragma unroll
  for (int rr = 0; rr < 16; ++rr) {
    d[rr] = Sw[(w * 16 + rr) * 16 + idx];
    mx = fmaxf(mx, d[rr]);
  }
  float e[16]; float ssum = 0.0f;
  #pragma unroll
  for (int rr = 0; rr < 16; ++rr) {
    e[rr] = xla_expf(__fsub_rn(d[rr], mx));
    ssum = __fadd_rn(ssum, e[rr]);
  }
  float acc = 0.0f;
  #pragma unroll
  for (int rr = 0; rr < 16; ++rr) {
    float p = e[rr] / ssum;
    acc = __fadd_rn(acc, __fmul_rn(p, (float)rr));
  }

  float lt0 = __shfl(acc, idx + 0);
  float lt1 = __shfl(acc, idx + 16);
  float lt2 = __shfl(acc, idx + 32);
  float lt3 = __shfl(acc, idx + 48);

  // ---- class top-2, 20 classes per worker (ascending, strict >) ----
  float best = -INFINITY, second = -INFINITY; int bi = 0;
  #pragma unroll 5
  for (int kk = 0; kk < 20; ++kk) {
    int c = 64 + w * 20 + kk;
    float v = Sw[c * 16 + idx];
    if (v > best)        { second = best; best = v; bi = w * 20 + kk; }
    else if (v > second) { second = v; }
  }
  // merge 4 workers: lower worker wins ties == global first-max semantics
  float gb = __shfl(best, idx + 0), gs = __shfl(second, idx + 0);
  int   gi = __shfl(bi,   idx + 0);
  #pragma unroll
  for (int qq = 1; qq < 4; ++qq) {
    float bq = __shfl(best, idx + qq * 16), sq = __shfl(second, idx + qq * 16);
    int   iq = __shfl(bi,   idx + qq * 16);
    if (bq > gb) { gs = fmaxf(gb, sq); gb = bq; gi = iq; }
    else         { gs = fmaxf(gs, bq); }
  }

  float conf = 0.0f; int cls = gi;
  if (__fsub_rn(gb, gs) < 1e-4f || gb > 5.0f) {
    // exact slow path (rare): identical to validated r1 80-sigmoid scan
    if (w == 0) {
      float bs = -INFINITY; int bj = 0;
      for (int kk = 0; kk < NCLS; ++kk) {
        float v = Sw[(64 + kk) * 16 + idx];
        float s2 = xla_sigmoid(v);
        if (s2 > bs) { bs = s2; bj = kk; }
      }
      conf = bs; cls = bj;
    }
  } else {
    conf = xla_sigmoid(gb);
  }

  if (w == 0) {
    float x1 = __fsub_rn(ax, lt0);
    float y1 = __fsub_rn(ay, lt1);
    float x2 = __fadd_rn(ax, lt2);
    float y2 = __fadd_rn(ay, lt3);
    float cx = __fmul_rn(__fadd_rn(x1, x2), 0.5f);
    float cy = __fmul_rn(__fadd_rn(y1, y2), 0.5f);
    float ww = __fsub_rn(x2, x1);
    float hh = __fsub_rn(y2, y1);
    int t = b * NA_TOT + lvlbase + a0w + idx;
    oboxes[t] = make_float4(__fmul_rn(cx, stridef), __fmul_rn(cy, stridef),
                            __fmul_rn(ww, stridef), __fmul_rn(hh, stridef));
    conf = (conf > CONFTHR) ? conf : 0.0f;
    oconf[t] = conf;
    oclsf[t] = (float)cls;
  }
}

// ---------------------------------------------------------------------------
// Kernel 2: per-image select (r12-validated verbatim — the 136.8 config).
// ---------------------------------------------------------------------------
struct __align__(16) K2Lds {
  unsigned long long sortkeys[SSORT];   // 16384 B (16B-aligned)
  unsigned confL[NA_TOT];               // 33600 B
  unsigned hist[16][257];               // 16448 B
  unsigned tot[257];
  unsigned Tarr[257];
};                                      // ~68.5 KB

__global__ __launch_bounds__(1024) void yolo_select_kernel(
    const float4* __restrict__ boxes, const float* __restrict__ conf,
    const float* __restrict__ clsf,
    float* __restrict__ g_rowd, unsigned long long* __restrict__ g_clsMask) {
  __shared__ K2Lds u;
  __shared__ unsigned s_need, s_prefix, s_found, s_B, s_scnt, s_cut, s_done;
  int b    = blockIdx.x;
  int tid  = threadIdx.x;
  int lane = tid & 63;
  int wv   = tid >> 6;
  const unsigned* confu = (const unsigned*)conf + (size_t)b * NA_TOT;
  float* rowd = g_rowd + (size_t)b * 1024 * 8;
  unsigned long long* cm = g_clsMask + (size_t)b * (NCLS * 16);

  // ---- P0: stage conf bits; zero ws outputs ----
  for (int i = tid; i < NA_TOT; i += 1024) u.confL[i] = confu[i];
  {
    float4 z4 = make_float4(0.f, 0.f, 0.f, 0.f);
    float4* gr = (float4*)rowd;
    for (int k = tid; k < 2048; k += 1024) gr[k] = z4;
  }
  for (int i = tid; i < NCLS * 16; i += 1024) cm[i] = 0ull;
  if (tid == 0) { s_need = 1024; s_prefix = 0; s_cut = 0; s_done = 0; s_scnt = 0; }
  __syncthreads();

  // ---- P1: adaptive 8-bit radix descent (validated r5-r16) ----
  for (int lv = 0; lv < 4; ++lv) {
    __syncthreads();
    if (s_done) break;                          // uniform
    for (int i = tid; i < 16 * 257; i += 1024) ((unsigned*)u.hist)[i] = 0;
    if (tid == 0) { s_found = 0; s_B = 0; }
    __syncthreads();
    unsigned pfx = s_prefix;
    for (int it = 0; it < 9; ++it) {
      int i = tid + it * 1024;
      unsigned c = (i < NA_TOT) ? u.confL[i] : 0u;
      bool in; unsigned bin;
      if (lv == 0)      { in = true;                bin = c >> 23; }
      else if (lv == 1) { in = ((c >> 23) == pfx);  bin = (c >> 15) & 0xFF; }
      else if (lv == 2) { in = ((c >> 15) == pfx);  bin = (c >> 7) & 0xFF; }
      else              { in = ((c >> 7)  == pfx);  bin = c & 0x7F; }
      bool act = (c != 0) && in;
      unsigned long long ab = __ballot(act);
      if (ab) {                                 // wave-uniform branch
        int fl = __ffsll(ab) - 1;
        unsigned fbin = __shfl(bin, fl);
        unsigned long long same = __ballot(act && (bin == fbin));
        if (same == ab) {
          if (lane == fl) atomicAdd(&u.hist[wv][fbin], (unsigned)__popcll(ab));
        } else if (act) {
          atomicAdd(&u.hist[wv][bin], 1u);
        }
      }
    }
    __syncthreads();
    if (tid < 256) {
      unsigned s = 0;
      #pragma unroll
      for (int q = 0; q < 16; ++q) s += u.hist[q][tid];
      u.tot[tid] = s;
    }
    __syncthreads();
    if (tid < 64) {
      unsigned carry = 0;
      if (tid == 0) u.Tarr[256] = 0;
      for (int ch = 3; ch >= 0; --ch) {
        int bb = ch * 64 + tid;
        unsigned v = u.tot[bb];
        #pragma unroll
        for (int off = 1; off < 64; off <<= 1) {
          unsigned t2 = __shfl_down(v, off);
          if (tid + off < 64) v += t2;
        }
        u.Tarr[bb] = v + carry;
        carry += __shfl(v, 0);
      }
    }
    __syncthreads();
    unsigned need = s_need;
    if (tid < 256) {
      unsigned h = u.tot[tid];
      if (h > 0 && u.Tarr[tid + 1] < need && u.Tarr[tid + 1] + h >= need) {
        s_B = (unsigned)tid; s_found = 1;
      }
    }
    __syncthreads();
    if (tid == 0) {
      if (!s_found) { s_cut = 1; s_done = 1; }
      else {
        unsigned B = s_B;
        unsigned selcnt = (1024u - need) + u.Tarr[B];
        if (selcnt <= (unsigned)RANKCAP || lv == 3) {
          s_done = 1;
          if (lv == 0)      s_cut = B << 23;
          else if (lv == 1) s_cut = (s_prefix << 23) | (B << 15);
          else if (lv == 2) s_cut = (s_prefix << 15) | (B << 7);
          else              s_cut = (s_prefix << 7)  | B;
        } else {
          s_need   = need - u.Tarr[B + 1];
          s_prefix = (s_prefix << 8) | B;
        }
      }
    }
  }
  __syncthreads();

  // ---- P2: ballot-aggregated compact ----
  unsigned cut = s_cut;
  for (int it = 0; it < 9; ++it) {
    int i = tid + it * 1024;
    unsigned c = (i < NA_TOT) ? u.confL[i] : 0u;
    bool sel = (c != 0 && c >= cut);
    unsigned long long bal = __ballot(sel);
    unsigned base2 = 0;
    if (lane == 0 && bal) base2 = atomicAdd(&s_scnt, (unsigned)__popcll(bal));
    base2 = __shfl(base2, 0);
    if (sel) {
      unsigned p = base2 + (unsigned)__popcll(bal & ((1ull << lane) - 1ull));
      if (p < SSORT)
        u.sortkeys[p] = ((unsigned long long)c << 32) |
                        (unsigned long long)(0xFFFFFFFFu - (unsigned)i);
    }
  }
  __syncthreads();
  unsigned scnt = s_scnt; if (scnt > SSORT) scnt = SSORT;
  unsigned snp = (scnt + 1u) & ~1u;
  if (tid == 0 && (scnt & 1u)) u.sortkeys[scnt] = 0ull;  // pad for b128
  __syncthreads();

  // ---- P3: rank-by-count (b128 LDS broadcast; validated) + scatter ----
  for (unsigned e = tid; e < scnt; e += 1024) {
    unsigned long long mykey = u.sortkeys[e];
    unsigned r = 0;
    #pragma unroll 4
    for (unsigned j = 0; j < snp; j += 2) {
      ulonglong2 kk = *reinterpret_cast<const ulonglong2*>(&u.sortkeys[j]);
      r += (kk.x > mykey) ? 1u : 0u;
      r += (kk.y > mykey) ? 1u : 0u;
    }
    if (r < 1024) {                             // == lax.top_k truncation
      unsigned a = 0xFFFFFFFFu - (unsigned)(mykey & 0xFFFFFFFFull);
      float4 cb = boxes[(size_t)b * NA_TOT + a];
      float cls = clsf[(size_t)b * NA_TOT + a];
      float4* gr = (float4*)(rowd + (size_t)r * 8);
      gr[0] = cb;
      gr[1] = make_float4(__uint_as_float((unsigned)(mykey >> 32)), cls, 0.f, 0.f);
      atomicOr(&cm[(int)cls * 16 + (r >> 6)], 1ull << (r & 63));
    }
  }
}

// ---------------------------------------------------------------------------
// Kernel 3: per-image NMS (r12-validated verbatim): parallel row build +
// per-class-parallel walks + parallel popcount emit + sticky tail.
// ---------------------------------------------------------------------------
struct K3Lds {
  unsigned long long rows[1024][16];    // 131072 B, col-swizzled: phys = q^(tid&15)
  float    rowdata[1024][6];            //  24576 B
  unsigned long long am[16];            //    128 B
};                                      // ~155.8 KB

__global__ __launch_bounds__(1024) void yolo_nms_kernel(
    const float* __restrict__ g_rowd,
    const unsigned long long* __restrict__ g_clsMask,
    float* __restrict__ out) {
  __shared__ K3Lds u;
  __shared__ unsigned s_sticky, s_fill;
  int b    = blockIdx.x;
  int tid  = threadIdx.x;
  const unsigned long long* cm = g_clsMask + (size_t)b * (NCLS * 16);

  {
    const float4* gr = (const float4*)(g_rowd + ((size_t)b * 1024 + tid) * 8);
    float4 v0 = gr[0];
    float4 v1 = gr[1];
    u.rowdata[tid][0] = v0.x; u.rowdata[tid][1] = v0.y;
    u.rowdata[tid][2] = v0.z; u.rowdata[tid][3] = v0.w;
    u.rowdata[tid][4] = v1.x; u.rowdata[tid][5] = v1.y;
  }
  {
    unsigned long long* flat = &u.rows[0][0];
    for (int k = tid; k < 1024 * 16; k += 1024) flat[k] = 0ull;
  }
  if (tid < 16) u.am[tid] = 0ull;
  if (tid == 0) { s_sticky = 0xFFFFFFFFu; s_fill = 0; }
  __syncthreads();

  // ---- build suppression-bit rows (same-class pairs; exact IoU sequence) ----
  {
    float cls = u.rowdata[tid][5];
    int c = (int)cls;
    const unsigned long long* cmask = cm + c * 16;
    bool valid = (cmask[tid >> 6] >> (tid & 63)) & 1ull;
    if (valid) {
      float bx0 = u.rowdata[tid][0], by0 = u.rowdata[tid][1];
      float bw0 = u.rowdata[tid][2], bh0 = u.rowdata[tid][3];
      float off = __fmul_rn(cls, 7680.0f);
      float hw  = __fmul_rn(bw0, 0.5f), hh = __fmul_rn(bh0, 0.5f);
      float wx1 = __fadd_rn(__fsub_rn(bx0, hw), off);
      float wy1 = __fadd_rn(__fsub_rn(by0, hh), off);
      float wx2 = __fadd_rn(__fadd_rn(bx0, hw), off);
      float wy2 = __fadd_rn(__fadd_rn(by0, hh), off);
      float a1  = __fmul_rn(__fsub_rn(wx2, wx1), __fsub_rn(wy2, wy1));
      int sw = tid & 15;
      for (int q = 0; q < 16; ++q) {
        unsigned long long m = cmask[q];
        while (m) {
          int bit = __ffsll(m) - 1;
          m &= m - 1ull;
          int j = q * 64 + bit;
          float jx = u.rowdata[j][0], jy = u.rowdata[j][1];
          float jw = u.rowdata[j][2], jh = u.rowdata[j][3];
          float jhw = __fmul_rn(jw, 0.5f), jhh = __fmul_rn(jh, 0.5f);
          float jx1 = __fadd_rn(__fsub_rn(jx, jhw), off);
          float jy1 = __fadd_rn(__fsub_rn(jy, jhh), off);
          float jx2 = __fadd_rn(__fadd_rn(jx, jhw), off);
          float jy2 = __fadd_rn(__fadd_rn(jy, jhh), off);
          float ltx = fmaxf(wx1, jx1), lty = fmaxf(wy1, jy1);
          float rbx = fminf(wx2, jx2), rby = fminf(wy2, jy2);
          float iw = fmaxf(__fsub_rn(rbx, ltx), 0.0f);
          float ih = fmaxf(__fsub_rn(rby, lty), 0.0f);
          float inter = __fmul_rn(iw, ih);
          float a2 = __fmul_rn(__fsub_rn(jx2, jx1), __fsub_rn(jy2, jy1));
          float den = __fadd_rn(__fsub_rn(__fadd_rn(a1, a2), inter), 1e-7f);
          float iou = inter / den;
          if (iou > 0.7f)
            u.rows[tid][(j >> 6) ^ sw] |= (1ull << (j & 63));
        }
      }
    }
  }
  __syncthreads();

  // ---- per-class-parallel walks (80 threads; register alive masks) ----
  if (tid < NCLS) {
    const unsigned long long* cmask = cm + tid * 16;
    unsigned long long alive[16];
    bool any = false;
    #pragma unroll
    for (int q = 0; q < 16; ++q) { alive[q] = cmask[q]; any |= (alive[q] != 0ull); }
    while (any) {
      int r = -1;
      #pragma unroll
      for (int q = 0; q < 16; ++q)
        if (r < 0 && alive[q]) r = q * 64 + (__ffsll(alive[q]) - 1);
      atomicOr(&u.am[r >> 6], 1ull << (r & 63));
      int sw = r & 15;
      unsigned long long selfw = u.rows[r][(r >> 6) ^ sw];
      bool selfbit = (selfw >> (r & 63)) & 1ull;
      if (!selfbit) { atomicMin(&s_sticky, (unsigned)r); break; }  // sticky
      any = false;
      #pragma unroll
      for (int q = 0; q < 16; ++q) {
        alive[q] &= ~u.rows[r][q ^ sw];
        any |= (alive[q] != 0ull);
      }
    }
  }
  __syncthreads();

  // ---- parallel emit: survivor r -> row popc(am below r) ----
  unsigned rs = s_sticky;
  {
    unsigned r = (unsigned)tid;
    bool surv = (u.am[r >> 6] >> (r & 63)) & 1ull;
    if (surv && r <= rs) {
      unsigned e2 = 0;
      int hi = (int)(r >> 6);
      #pragma unroll
      for (int q = 0; q < 16; ++q) {
        unsigned long long m = u.am[q];
        if (q < hi)       e2 += (unsigned)__popcll(m);
        else if (q == hi) e2 += (unsigned)__popcll(m & ((1ull << (r & 63)) - 1ull));
      }
      if (e2 < MAXDET) {
        float* orow = out + (size_t)b * (MAXDET * 6) + (size_t)e2 * 6;
        orow[0] = u.rowdata[r][0];
        orow[1] = u.rowdata[r][1];
        orow[2] = u.rowdata[r][2];
        orow[3] = u.rowdata[r][3];
        orow[4] = u.rowdata[r][4];
        orow[5] = u.rowdata[r][5];
      }
    }
  }
  if (tid == 0) {
    unsigned fill;
    if (rs != 0xFFFFFFFFu) {
      unsigned es = 0;
      int hi = (int)(rs >> 6);
      #pragma unroll
      for (int q = 0; q < 16; ++q) {
        unsigned long long m = u.am[q];
        if (q < hi)       es += (unsigned)__popcll(m);
        else if (q == hi) es += (unsigned)__popcll(m & ((1ull << (rs & 63)) - 1ull));
      }
      fill = es + 1;
    } else {
      unsigned S = 0;
      #pragma unroll
      for (int q = 0; q < 16; ++q) S += (unsigned)__popcll(u.am[q]);
      fill = S;
    }
    s_fill = (fill > (unsigned)MAXDET) ? (unsigned)MAXDET : fill;
  }
  __syncthreads();

  {
    unsigned fill = s_fill;
    bool st = (rs != 0xFFFFFFFFu);
    float* orow = out + (size_t)b * (MAXDET * 6);
    for (int i = (int)fill * 6 + tid; i < MAXDET * 6; i += 1024) {
      float v = 0.0f;
      if (st) v = u.rowdata[rs][i - (i / 6) * 6];
      orow[i] = v;
    }
  }
}

extern "C" void kernel_launch(void* const* d_in, const int* in_sizes, int n_in,
                              void* d_out, int out_size, void* d_ws, size_t ws_size,
                              hipStream_t stream) {
  const float* f0 = (const float*)d_in[0];
  const float* f1 = (const float*)d_in[1];
  const float* f2 = (const float*)d_in[2];
  float* out = (float*)d_out;

  char* ws = (char*)d_ws;
  float4* boxes = (float4*)ws;                                       // 4,300,800
  float*  conf  = (float*)(ws + (size_t)NBATCH * NA_TOT * 16);       // 1,075,200
  float*  clsf  = (float*)(ws + (size_t)NBATCH * NA_TOT * 20);       // 1,075,200
  float*  rowd  = (float*)(ws + (size_t)NBATCH * NA_TOT * 24);       // 1,048,576
  unsigned long long* clsm =
      (unsigned long long*)(ws + (size_t)NBATCH * NA_TOT * 24 + 1048576); // 327,680

  yolo_decode_kernel<<<NBATCH * TILES_PER_IMG, 256, 0, stream>>>(
      f0, f1, f2, boxes, conf, clsf);
  yolo_select_kernel<<<NBATCH, 1024, 0, stream>>>(boxes, conf, clsf, rowd, clsm);
  yolo_nms_kernel<<<NBATCH, 1024, 0, stream>>>(rowd, clsm, out);
}

// Round 18
// 123.656 us; speedup vs baseline: 1.5703x; 1.0977x over previous
//
#include <hip/hip_runtime.h>
#include <stdint.h>

#define NCLS    80
#define NA_TOT  8400     // 6400 + 1600 + 400
#define NBATCH  32
#define MAXDET  300
#define SSORT   2048
#define RANKCAP 1536
#define CONFTHR 0.001f
#define TILES_PER_IMG 132   // 100 (L0) + 25 (L1) + 7 (L2, clamped)
#define GKCAP   2056        // per-image key slots (2048 + pad)

// ---------------------------------------------------------------------------
// Bit-exact reconstruction of XLA:CPU f32 exp (Eigen/Cephes pexp, no FMA) and
// logistic = 1/(1+exp(-x)). Validated absmax==0.0 rounds 1-17. DO NOT TOUCH.
// ---------------------------------------------------------------------------
__device__ __forceinline__ float xla_expf(float in) {
  const float exp_hi = 88.3762626647950f;
  const float exp_lo = -88.3762626647949f;
  const float LOG2EF = 1.44269504088896341f;
  const float C1 = 0.693359375f;
  const float C2 = -2.12194440e-4f;
  const float p0 = 1.9875691500E-4f, p1 = 1.3981999507E-3f, p2 = 8.3334519073E-3f;
  const float p3 = 4.1665795894E-2f, p4 = 1.6666665459E-1f, p5 = 5.0000001201E-1f;
  float x = fminf(fmaxf(in, exp_lo), exp_hi);
  float fx = floorf(__fadd_rn(__fmul_rn(x, LOG2EF), 0.5f));
  float tmp = __fmul_rn(C1, fx);
  float z   = __fmul_rn(C2, fx);
  x = __fsub_rn(x, tmp);
  x = __fsub_rn(x, z);
  float y = __fadd_rn(__fmul_rn(x, p0), p1);
  y = __fadd_rn(__fmul_rn(y, x), p2);
  y = __fadd_rn(__fmul_rn(y, x), p3);
  y = __fadd_rn(__fmul_rn(y, x), p4);
  y = __fadd_rn(__fmul_rn(y, x), p5);
  y = __fadd_rn(__fmul_rn(y, __fmul_rn(x, x)), x);
  y = __fadd_rn(1.0f, y);
  int m = (int)fx;
  float s = __uint_as_float((uint32_t)(m + 127) << 23);
  float r = __fmul_rn(y, s);
  return fmaxf(r, in);
}

__device__ __forceinline__ float xla_sigmoid(float v) {
  float e = xla_expf(-v);
  float den = __fadd_rn(1.0f, e);
  return 1.0f / den;
}

__device__ __forceinline__ void gload_lds16(const float* gp, float* lp) {
  __builtin_amdgcn_global_load_lds(
      (const __attribute__((address_space(1))) void*)gp,
      (__attribute__((address_space(3))) void*)lp, 16, 0, 0);
}

// ---------------------------------------------------------------------------
// Kernel 1: decode v4 — per-wave autonomy, barrier-free (r17-measured best).
// Verbatim r17.
// ---------------------------------------------------------------------------
__global__ __launch_bounds__(256) void yolo_decode_kernel(
    const float* __restrict__ f0, const float* __restrict__ f1,
    const float* __restrict__ f2,
    float4* __restrict__ oboxes, float* __restrict__ oconf,
    float* __restrict__ oclsf) {
  __shared__ float sm[4 * 144 * 16];            // 36,864 B -> 4 blocks/CU
  int bx  = blockIdx.x;
  int b   = bx / TILES_PER_IMG;
  int r   = bx - b * TILES_PER_IMG;
  int tid = threadIdx.x;
  int lane = tid & 63;
  int wv   = tid >> 6;

  const float* base; int Alvl, W, a0, lvlbase; float stridef;
  if (r < 100)      { base = f0 + (size_t)b * (144 * 6400); W = 80; Alvl = 6400;
                      a0 = r * 64; stridef = 8.0f; lvlbase = 0; }
  else if (r < 125) { base = f1 + (size_t)b * (144 * 1600); W = 40; Alvl = 1600;
                      a0 = (r - 100) * 64; stridef = 16.0f; lvlbase = 6400; }
  else              { base = f2 + (size_t)b * (144 * 400);  W = 20; Alvl = 400;
                      int aa = (r - 125) * 64; a0 = (aa + 64 <= 400) ? aa : 336;
                      stridef = 32.0f; lvlbase = 8000; }   // clamped overlap: benign

  int a0w = a0 + wv * 16;
  float* Sw = sm + wv * (144 * 16);

  #pragma unroll
  for (int k = 0; k < 9; ++k) {
    int ch = k * 16 + (lane >> 2);
    const float* gp = base + (size_t)ch * Alvl + a0w + (lane & 3) * 4;
    gload_lds16(gp, Sw + k * 256);
  }
  asm volatile("s_waitcnt vmcnt(0)" ::: "memory");
  __builtin_amdgcn_sched_barrier(0);

  int idx = lane & 15;
  int w   = lane >> 4;
  int ai  = a0w + idx;
  float ax = __fadd_rn((float)(ai % W), 0.5f);
  float ay = __fadd_rn((float)(ai / W), 0.5f);

  float d[16];
  float mx = -INFINITY;
  #pragma unroll
  for (int rr = 0; rr < 16; ++rr) {
    d[rr] = Sw[(w * 16 + rr) * 16 + idx];
    mx = fmaxf(mx, d[rr]);
  }
  float e[16]; float ssum = 0.0f;
  #pragma unroll
  for (int rr = 0; rr < 16; ++rr) {
    e[rr] = xla_expf(__fsub_rn(d[rr], mx));
    ssum = __fadd_rn(ssum, e[rr]);
  }
  float acc = 0.0f;
  #pragma unroll
  for (int rr = 0; rr < 16; ++rr) {
    float p = e[rr] / ssum;
    acc = __fadd_rn(acc, __fmul_rn(p, (float)rr));
  }

  float lt0 = __shfl(acc, idx + 0);
  float lt1 = __shfl(acc, idx + 16);
  float lt2 = __shfl(acc, idx + 32);
  float lt3 = __shfl(acc, idx + 48);

  float best = -INFINITY, second = -INFINITY; int bi = 0;
  #pragma unroll 5
  for (int kk = 0; kk < 20; ++kk) {
    int c = 64 + w * 20 + kk;
    float v = Sw[c * 16 + idx];
    if (v > best)        { second = best; best = v; bi = w * 20 + kk; }
    else if (v > second) { second = v; }
  }
  float gb = __shfl(best, idx + 0), gs = __shfl(second, idx + 0);
  int   gi = __shfl(bi,   idx + 0);
  #pragma unroll
  for (int qq = 1; qq < 4; ++qq) {
    float bq = __shfl(best, idx + qq * 16), sq = __shfl(second, idx + qq * 16);
    int   iq = __shfl(bi,   idx + qq * 16);
    if (bq > gb) { gs = fmaxf(gb, sq); gb = bq; gi = iq; }
    else         { gs = fmaxf(gs, bq); }
  }

  float conf = 0.0f; int cls = gi;
  if (__fsub_rn(gb, gs) < 1e-4f || gb > 5.0f) {
    if (w == 0) {
      float bs = -INFINITY; int bj = 0;
      for (int kk = 0; kk < NCLS; ++kk) {
        float v = Sw[(64 + kk) * 16 + idx];
        float s2 = xla_sigmoid(v);
        if (s2 > bs) { bs = s2; bj = kk; }
      }
      conf = bs; cls = bj;
    }
  } else {
    conf = xla_sigmoid(gb);
  }

  if (w == 0) {
    float x1 = __fsub_rn(ax, lt0);
    float y1 = __fsub_rn(ay, lt1);
    float x2 = __fadd_rn(ax, lt2);
    float y2 = __fadd_rn(ay, lt3);
    float cx = __fmul_rn(__fadd_rn(x1, x2), 0.5f);
    float cy = __fmul_rn(__fadd_rn(y1, y2), 0.5f);
    float ww = __fsub_rn(x2, x1);
    float hh = __fsub_rn(y2, y1);
    int t = b * NA_TOT + lvlbase + a0w + idx;
    oboxes[t] = make_float4(__fmul_rn(cx, stridef), __fmul_rn(cy, stridef),
                            __fmul_rn(ww, stridef), __fmul_rn(hh, stridef));
    conf = (conf > CONFTHR) ? conf : 0.0f;
    oconf[t] = conf;
    oclsf[t] = (float)cls;
  }
}

// ---------------------------------------------------------------------------
// Kernel 2a: per-image select (r12-validated descent + compact), keys to
// GLOBAL scratch; rank moved to K2b (which stages keys into its OWN LDS).
// ---------------------------------------------------------------------------
struct __align__(16) K2Lds {
  unsigned confL[NA_TOT];               // 33600 B
  unsigned hist[16][257];               // 16448 B
  unsigned tot[257];
  unsigned Tarr[257];
};                                      // ~52 KB

__global__ __launch_bounds__(1024) void yolo_select_kernel(
    const float* __restrict__ conf,
    unsigned long long* __restrict__ g_keys, unsigned* __restrict__ g_scnt,
    float* __restrict__ g_rowd, unsigned long long* __restrict__ g_clsMask) {
  __shared__ K2Lds u;
  __shared__ unsigned s_need, s_prefix, s_found, s_B, s_scnt, s_cut, s_done;
  int b    = blockIdx.x;
  int tid  = threadIdx.x;
  int lane = tid & 63;
  int wv   = tid >> 6;
  const unsigned* confu = (const unsigned*)conf + (size_t)b * NA_TOT;
  unsigned long long* gk = g_keys + (size_t)b * GKCAP;

  // ---- P0: stage conf bits; zero downstream ws state ----
  for (int i = tid; i < NA_TOT; i += 1024) u.confL[i] = confu[i];
  {
    float4 z4 = make_float4(0.f, 0.f, 0.f, 0.f);
    float4* gr = (float4*)(g_rowd + (size_t)b * 1024 * 8);
    for (int k = tid; k < 2048; k += 1024) gr[k] = z4;
  }
  for (int i = tid; i < NCLS * 16; i += 1024)
    g_clsMask[(size_t)b * (NCLS * 16) + i] = 0ull;
  if (tid == 0) { s_need = 1024; s_prefix = 0; s_cut = 0; s_done = 0; s_scnt = 0; }
  __syncthreads();

  // ---- P1: adaptive 8-bit radix descent (validated r5-r17, verbatim) ----
  for (int lv = 0; lv < 4; ++lv) {
    __syncthreads();
    if (s_done) break;                          // uniform
    for (int i = tid; i < 16 * 257; i += 1024) ((unsigned*)u.hist)[i] = 0;
    if (tid == 0) { s_found = 0; s_B = 0; }
    __syncthreads();
    unsigned pfx = s_prefix;
    for (int it = 0; it < 9; ++it) {
      int i = tid + it * 1024;
      unsigned c = (i < NA_TOT) ? u.confL[i] : 0u;
      bool in; unsigned bin;
      if (lv == 0)      { in = true;                bin = c >> 23; }
      else if (lv == 1) { in = ((c >> 23) == pfx);  bin = (c >> 15) & 0xFF; }
      else if (lv == 2) { in = ((c >> 15) == pfx);  bin = (c >> 7) & 0xFF; }
      else              { in = ((c >> 7)  == pfx);  bin = c & 0x7F; }
      bool act = (c != 0) && in;
      unsigned long long ab = __ballot(act);
      if (ab) {                                 // wave-uniform branch
        int fl = __ffsll(ab) - 1;
        unsigned fbin = __shfl(bin, fl);
        unsigned long long same = __ballot(act && (bin == fbin));
        if (same == ab) {
          if (lane == fl) atomicAdd(&u.hist[wv][fbin], (unsigned)__popcll(ab));
        } else if (act) {
          atomicAdd(&u.hist[wv][bin], 1u);
        }
      }
    }
    __syncthreads();
    if (tid < 256) {
      unsigned s = 0;
      #pragma unroll
      for (int q = 0; q < 16; ++q) s += u.hist[q][tid];
      u.tot[tid] = s;
    }
    __syncthreads();
    if (tid < 64) {
      unsigned carry = 0;
      if (tid == 0) u.Tarr[256] = 0;
      for (int ch = 3; ch >= 0; --ch) {
        int bb = ch * 64 + tid;
        unsigned v = u.tot[bb];
        #pragma unroll
        for (int off = 1; off < 64; off <<= 1) {
          unsigned t2 = __shfl_down(v, off);
          if (tid + off < 64) v += t2;
        }
        u.Tarr[bb] = v + carry;
        carry += __shfl(v, 0);
      }
    }
    __syncthreads();
    unsigned need = s_need;
    if (tid < 256) {
      unsigned h = u.tot[tid];
      if (h > 0 && u.Tarr[tid + 1] < need && u.Tarr[tid + 1] + h >= need) {
        s_B = (unsigned)tid; s_found = 1;
      }
    }
    __syncthreads();
    if (tid == 0) {
      if (!s_found) { s_cut = 1; s_done = 1; }
      else {
        unsigned B = s_B;
        unsigned selcnt = (1024u - need) + u.Tarr[B];
        if (selcnt <= (unsigned)RANKCAP || lv == 3) {
          s_done = 1;
          if (lv == 0)      s_cut = B << 23;
          else if (lv == 1) s_cut = (s_prefix << 23) | (B << 15);
          else if (lv == 2) s_cut = (s_prefix << 15) | (B << 7);
          else              s_cut = (s_prefix << 7)  | B;
        } else {
          s_need   = need - u.Tarr[B + 1];
          s_prefix = (s_prefix << 8) | B;
        }
      }
    }
  }
  __syncthreads();

  // ---- P2: ballot-aggregated compact -> GLOBAL keys ----
  unsigned cut = s_cut;
  for (int it = 0; it < 9; ++it) {
    int i = tid + it * 1024;
    unsigned c = (i < NA_TOT) ? u.confL[i] : 0u;
    bool sel = (c != 0 && c >= cut);
    unsigned long long bal = __ballot(sel);
    unsigned base2 = 0;
    if (lane == 0 && bal) base2 = atomicAdd(&s_scnt, (unsigned)__popcll(bal));
    base2 = __shfl(base2, 0);
    if (sel) {
      unsigned p = base2 + (unsigned)__popcll(bal & ((1ull << lane) - 1ull));
      if (p < SSORT)
        gk[p] = ((unsigned long long)c << 32) |
                (unsigned long long)(0xFFFFFFFFu - (unsigned)i);
    }
  }
  __syncthreads();
  if (tid == 0) {
    unsigned sc = s_scnt; if (sc > SSORT) sc = SSORT;
    g_scnt[b] = sc;
    if (sc & 1u) gk[sc] = 0ull;                 // pad for paired reads
  }
}

// ---------------------------------------------------------------------------
// Kernel 2b: rank + scatter, 8 blocks/image. Each block STAGES the full key
// array into its own LDS (coalesced ~12 KB), then ranks via LDS broadcast
// (the r12/r15-proven fast path) at 1/8 the per-CU port pressure.
// Identical compare set -> identical ranks -> identical scatter semantics.
// ---------------------------------------------------------------------------
__global__ __launch_bounds__(256) void yolo_rank_kernel(
    const unsigned long long* __restrict__ g_keys,
    const unsigned* __restrict__ g_scnt,
    const float4* __restrict__ boxes, const float* __restrict__ clsf,
    float* __restrict__ g_rowd, unsigned long long* __restrict__ g_clsMask) {
  __shared__ __align__(16) unsigned long long lk[GKCAP];   // 16,448 B
  int bx   = blockIdx.x;
  int b    = bx >> 3;
  int part = bx & 7;
  int tid  = threadIdx.x;
  const unsigned long long* gk = g_keys + (size_t)b * GKCAP;
  unsigned scnt = g_scnt[b];                    // uniform
  unsigned snp  = (scnt + 1u) & ~1u;

  for (unsigned i = tid; i < snp; i += 256) lk[i] = gk[i];   // coalesced
  __syncthreads();

  unsigned e = (unsigned)(part * 256 + tid);    // 8*256 = 2048 >= scnt
  if (e >= scnt) return;
  unsigned long long mykey = lk[e];
  unsigned r = 0;
  #pragma unroll 4
  for (unsigned j = 0; j < snp; j += 2) {       // LDS b128 broadcast
    ulonglong2 kk = *reinterpret_cast<const ulonglong2*>(&lk[j]);
    r += (kk.x > mykey) ? 1u : 0u;
    r += (kk.y > mykey) ? 1u : 0u;
  }

  if (r < 1024) {                               // == lax.top_k truncation
    unsigned a = 0xFFFFFFFFu - (unsigned)(mykey & 0xFFFFFFFFull);
    float4 cb = boxes[(size_t)b * NA_TOT + a];
    float cls = clsf[(size_t)b * NA_TOT + a];
    float* rowd = g_rowd + (size_t)b * 1024 * 8;
    float4* gr = (float4*)(rowd + (size_t)r * 8);
    gr[0] = cb;
    gr[1] = make_float4(__uint_as_float((unsigned)(mykey >> 32)), cls, 0.f, 0.f);
    atomicOr(&g_clsMask[(size_t)b * (NCLS * 16) + (int)cls * 16 + (r >> 6)],
             1ull << (r & 63));
  }
}

// ---------------------------------------------------------------------------
// Kernel 3: per-image NMS (r12-validated verbatim): parallel row build +
// per-class-parallel walks + parallel popcount emit + sticky tail.
// ---------------------------------------------------------------------------
struct K3Lds {
  unsigned long long rows[1024][16];    // 131072 B, col-swizzled: phys = q^(tid&15)
  float    rowdata[1024][6];            //  24576 B
  unsigned long long am[16];            //    128 B
};                                      // ~155.8 KB

__global__ __launch_bounds__(1024) void yolo_nms_kernel(
    const float* __restrict__ g_rowd,
    const unsigned long long* __restrict__ g_clsMask,
    float* __restrict__ out) {
  __shared__ K3Lds u;
  __shared__ unsigned s_sticky, s_fill;
  int b    = blockIdx.x;
  int tid  = threadIdx.x;
  const unsigned long long* cm = g_clsMask + (size_t)b * (NCLS * 16);

  {
    const float4* gr = (const float4*)(g_rowd + ((size_t)b * 1024 + tid) * 8);
    float4 v0 = gr[0];
    float4 v1 = gr[1];
    u.rowdata[tid][0] = v0.x; u.rowdata[tid][1] = v0.y;
    u.rowdata[tid][2] = v0.z; u.rowdata[tid][3] = v0.w;
    u.rowdata[tid][4] = v1.x; u.rowdata[tid][5] = v1.y;
  }
  {
    unsigned long long* flat = &u.rows[0][0];
    for (int k = tid; k < 1024 * 16; k += 1024) flat[k] = 0ull;
  }
  if (tid < 16) u.am[tid] = 0ull;
  if (tid == 0) { s_sticky = 0xFFFFFFFFu; s_fill = 0; }
  __syncthreads();

  // ---- build suppression-bit rows (same-class pairs; exact IoU sequence) ----
  {
    float cls = u.rowdata[tid][5];
    int c = (int)cls;
    const unsigned long long* cmask = cm + c * 16;
    bool valid = (cmask[tid >> 6] >> (tid & 63)) & 1ull;
    if (valid) {
      float bx0 = u.rowdata[tid][0], by0 = u.rowdata[tid][1];
      float bw0 = u.rowdata[tid][2], bh0 = u.rowdata[tid][3];
      float off = __fmul_rn(cls, 7680.0f);
      float hw  = __fmul_rn(bw0, 0.5f), hh = __fmul_rn(bh0, 0.5f);
      float wx1 = __fadd_rn(__fsub_rn(bx0, hw), off);
      float wy1 = __fadd_rn(__fsub_rn(by0, hh), off);
      float wx2 = __fadd_rn(__fadd_rn(bx0, hw), off);
      float wy2 = __fadd_rn(__fadd_rn(by0, hh), off);
      float a1  = __fmul_rn(__fsub_rn(wx2, wx1), __fsub_rn(wy2, wy1));
      int sw = tid & 15;
      for (int q = 0; q < 16; ++q) {
        unsigned long long m = cmask[q];
        while (m) {
          int bit = __ffsll(m) - 1;
          m &= m - 1ull;
          int j = q * 64 + bit;
          float jx = u.rowdata[j][0], jy = u.rowdata[j][1];
          float jw = u.rowdata[j][2], jh = u.rowdata[j][3];
          float jhw = __fmul_rn(jw, 0.5f), jhh = __fmul_rn(jh, 0.5f);
          float jx1 = __fadd_rn(__fsub_rn(jx, jhw), off);
          float jy1 = __fadd_rn(__fsub_rn(jy, jhh), off);
          float jx2 = __fadd_rn(__fadd_rn(jx, jhw), off);
          float jy2 = __fadd_rn(__fadd_rn(jy, jhh), off);
          float ltx = fmaxf(wx1, jx1), lty = fmaxf(wy1, jy1);
          float rbx = fminf(wx2, jx2), rby = fminf(wy2, jy2);
          float iw = fmaxf(__fsub_rn(rbx, ltx), 0.0f);
          float ih = fmaxf(__fsub_rn(rby, lty), 0.0f);
          float inter = __fmul_rn(iw, ih);
          float a2 = __fmul_rn(__fsub_rn(jx2, jx1), __fsub_rn(jy2, jy1));
          float den = __fadd_rn(__fsub_rn(__fadd_rn(a1, a2), inter), 1e-7f);
          float iou = inter / den;
          if (iou > 0.7f)
            u.rows[tid][(j >> 6) ^ sw] |= (1ull << (j & 63));
        }
      }
    }
  }
  __syncthreads();

  // ---- per-class-parallel walks (80 threads; register alive masks) ----
  if (tid < NCLS) {
    const unsigned long long* cmask = cm + tid * 16;
    unsigned long long alive[16];
    bool any = false;
    #pragma unroll
    for (int q = 0; q < 16; ++q) { alive[q] = cmask[q]; any |= (alive[q] != 0ull); }
    while (any) {
      int r = -1;
      #pragma unroll
      for (int q = 0; q < 16; ++q)
        if (r < 0 && alive[q]) r = q * 64 + (__ffsll(alive[q]) - 1);
      atomicOr(&u.am[r >> 6], 1ull << (r & 63));
      int sw = r & 15;
      unsigned long long selfw = u.rows[r][(r >> 6) ^ sw];
      bool selfbit = (selfw >> (r & 63)) & 1ull;
      if (!selfbit) { atomicMin(&s_sticky, (unsigned)r); break; }  // sticky
      any = false;
      #pragma unroll
      for (int q = 0; q < 16; ++q) {
        alive[q] &= ~u.rows[r][q ^ sw];
        any |= (alive[q] != 0ull);
      }
    }
  }
  __syncthreads();

  // ---- parallel emit: survivor r -> row popc(am below r) ----
  unsigned rs = s_sticky;
  {
    unsigned r = (unsigned)tid;
    bool surv = (u.am[r >> 6] >> (r & 63)) & 1ull;
    if (surv && r <= rs) {
      unsigned e2 = 0;
      int hi = (int)(r >> 6);
      #pragma unroll
      for (int q = 0; q < 16; ++q) {
        unsigned long long m = u.am[q];
        if (q < hi)       e2 += (unsigned)__popcll(m);
        else if (q == hi) e2 += (unsigned)__popcll(m & ((1ull << (r & 63)) - 1ull));
      }
      if (e2 < MAXDET) {
        float* orow = out + (size_t)b * (MAXDET * 6) + (size_t)e2 * 6;
        orow[0] = u.rowdata[r][0];
        orow[1] = u.rowdata[r][1];
        orow[2] = u.rowdata[r][2];
        orow[3] = u.rowdata[r][3];
        orow[4] = u.rowdata[r][4];
        orow[5] = u.rowdata[r][5];
      }
    }
  }
  if (tid == 0) {
    unsigned fill;
    if (rs != 0xFFFFFFFFu) {
      unsigned es = 0;
      int hi = (int)(rs >> 6);
      #pragma unroll
      for (int q = 0; q < 16; ++q) {
        unsigned long long m = u.am[q];
        if (q < hi)       es += (unsigned)__popcll(m);
        else if (q == hi) es += (unsigned)__popcll(m & ((1ull << (rs & 63)) - 1ull));
      }
      fill = es + 1;
    } else {
      unsigned S = 0;
      #pragma unroll
      for (int q = 0; q < 16; ++q) S += (unsigned)__popcll(u.am[q]);
      fill = S;
    }
    s_fill = (fill > (unsigned)MAXDET) ? (unsigned)MAXDET : fill;
  }
  __syncthreads();

  {
    unsigned fill = s_fill;
    bool st = (rs != 0xFFFFFFFFu);
    float* orow = out + (size_t)b * (MAXDET * 6);
    for (int i = (int)fill * 6 + tid; i < MAXDET * 6; i += 1024) {
      float v = 0.0f;
      if (st) v = u.rowdata[rs][i - (i / 6) * 6];
      orow[i] = v;
    }
  }
}

extern "C" void kernel_launch(void* const* d_in, const int* in_sizes, int n_in,
                              void* d_out, int out_size, void* d_ws, size_t ws_size,
                              hipStream_t stream) {
  const float* f0 = (const float*)d_in[0];
  const float* f1 = (const float*)d_in[1];
  const float* f2 = (const float*)d_in[2];
  float* out = (float*)d_out;

  char* ws = (char*)d_ws;
  float4* boxes = (float4*)ws;                                       // 4,300,800
  float*  conf  = (float*)(ws + (size_t)NBATCH * NA_TOT * 16);       // 1,075,200
  float*  clsf  = (float*)(ws + (size_t)NBATCH * NA_TOT * 20);       // 1,075,200
  size_t off = (size_t)NBATCH * NA_TOT * 24;                         // 6,451,200
  float*  rowd  = (float*)(ws + off);                         off += 1048576;
  unsigned long long* clsm  = (unsigned long long*)(ws + off); off += 327680;
  unsigned long long* gkeys = (unsigned long long*)(ws + off); off += (size_t)NBATCH * GKCAP * 8;
  unsigned* scnts = (unsigned*)(ws + off);

  yolo_decode_kernel<<<NBATCH * TILES_PER_IMG, 256, 0, stream>>>(
      f0, f1, f2, boxes, conf, clsf);
  yolo_select_kernel<<<NBATCH, 1024, 0, stream>>>(conf, gkeys, scnts,
                                                  rowd, clsm);
  yolo_rank_kernel<<<NBATCH * 8, 256, 0, stream>>>(gkeys, scnts, boxes, clsf,
                                                   rowd, clsm);
  yolo_nms_kernel<<<NBATCH, 1024, 0, stream>>>(rowd, clsm, out);
}